// Round 12
// baseline (450.760 us; speedup 1.0000x reference)
//
#include <hip/hip_runtime.h>
#include <math.h>

// ============================================================================
// BitNet transformer block, MI355X (gfx950).  Round 12.
// R11 -> R12: BARRIER-FREE attention. R11 analysis: 8-wave lockstep blocks =
// 1 chain each, 2 chains/CU, 3380 cyc/slot latency-bound. K/V is L2-resident
// (FETCH 12MB) -> staging is pure overhead (common-mistake #7). Now: K/V
// fragments read DIRECTLY from global/L2 (16x64B segments per instr), no
// LDS staging, no barriers, every wave independent. LDS = 8KB P-buf only;
// __launch_bounds__(256,4) -> 16 independent wave-chains/CU.
// ws layout (MB = 2^20): unchanged from R11.
// ============================================================================

typedef unsigned short u16;
typedef unsigned int u32;
typedef __attribute__((ext_vector_type(2))) unsigned int u32x2;
typedef __attribute__((ext_vector_type(4))) float f32x4;
typedef __attribute__((ext_vector_type(4))) unsigned short u16x4;
typedef __attribute__((ext_vector_type(8))) unsigned short u16x8;
typedef __attribute__((ext_vector_type(8))) __bf16 bf16x8;

#define DEV static __device__ __forceinline__

DEV float bf2f(u16 u) { union { unsigned i; float f; } c; c.i = ((unsigned)u) << 16; return c.f; }
DEV u16 f2bf(float f) { __bf16 b = (__bf16)f; return __builtin_bit_cast(u16, b); }
DEV float fexp2(float x) { float r; asm("v_exp_f32 %0, %1" : "=v"(r) : "v"(x)); return r; }
DEV u32 cvtpk(float lo, float hi) {
  u32 r; asm("v_cvt_pk_bf16_f32 %0, %1, %2" : "=v"(r) : "v"(lo), "v"(hi)); return r;
}
DEV bf16x8 ld8(const u16* p) { return __builtin_bit_cast(bf16x8, *(const u16x8*)p); }

DEV void gload16(const void* g, void* l) {
  __builtin_amdgcn_global_load_lds((__attribute__((address_space(1))) void*)g,
                                   (__attribute__((address_space(3))) void*)l,
                                   16, 0, 0);
}

// ---------------------------------------------------------------------------
// Weight prep: sign(w) -> bf16 {+1,-1,0}, block-partial |w| sums.
// wi 4/5 (w1/w2) interleave at 16-row granularity into one buffer at +8MB.
// wi==7: rmsnorm+act_quant of x (16 rows per block) - free overlap.
// ---------------------------------------------------------------------------
__global__ __launch_bounds__(256) void convert_sign_all(
    const float* __restrict__ w0, const float* __restrict__ w1,
    const float* __restrict__ w2, const float* __restrict__ w3,
    const float* __restrict__ w4, const float* __restrict__ w5,
    const float* __restrict__ w6, u16* __restrict__ sgn_base,
    float* __restrict__ partial,
    const float* __restrict__ x, const float* __restrict__ g1,
    u16* __restrict__ hq) {
  __shared__ float red[4];
  const int wi = blockIdx.y;
  const int t = threadIdx.x;

  if (wi == 7) {  // rmsnorm + act_quant for rows 16*bx .. +15
#pragma unroll 1
    for (int rr = 0; rr < 16; ++rr) {
      const int row = blockIdx.x * 16 + rr;
      f32x4 v = ((const f32x4*)(x + (size_t)row * 1024))[t];
      float ss = v[0] * v[0] + v[1] * v[1] + v[2] * v[2] + v[3] * v[3];
#pragma unroll
      for (int off = 32; off >= 1; off >>= 1) ss += __shfl_xor(ss, off);
      if ((t & 63) == 0) red[t >> 6] = ss;
      __syncthreads();
      float tot = red[0] + red[1] + red[2] + red[3];
      __syncthreads();
      float rinv = rsqrtf(tot * (1.f / 1024.f) + 1e-6f);
      f32x4 gg = ((const f32x4*)g1)[t];
      float n[4];
#pragma unroll
      for (int j = 0; j < 4; ++j) n[j] = v[j] * rinv * gg[j];
      float gm = fmaxf(fmaxf(fabsf(n[0]), fabsf(n[1])), fmaxf(fabsf(n[2]), fabsf(n[3])));
#pragma unroll
      for (int off = 1; off <= 8; off <<= 1) gm = fmaxf(gm, __shfl_xor(gm, off));
      float s = fmaxf(gm, 1e-5f) / 127.0f;
      u16x4 o;
#pragma unroll
      for (int j = 0; j < 4; ++j) {
        float q = fminf(fmaxf(rintf(n[j] / s), -127.f), 127.f) * s;
        o[j] = f2bf(q);
      }
      ((u16x4*)hq)[(size_t)row * 256 + t] = o;
    }
    return;
  }

  const float* srcs[7] = {w0, w1, w2, w3, w4, w5, w6};
  const size_t offs[7] = {0, 1048576, 2097152, 3145728, 4194304, 4194304, 12582912};
  const float* w = srcs[wi];
  u16* sgn = sgn_base + offs[wi];
  const int n4 = (wi < 4) ? 262144 : 1048576;
  const bool ilv = (wi == 4) || (wi == 5);
  const int ilv_add = (wi == 5) ? 16 : 0;

  float s = 0.f;
  for (int i = blockIdx.x * 256 + t; i < n4; i += 256 * 256) {
    f32x4 v = ((const f32x4*)w)[i];
    u16x4 o;
#pragma unroll
    for (int j = 0; j < 4; ++j) {
      float f = v[j];
      o[j] = f > 0.f ? (u16)0x3F80 : (f < 0.f ? (u16)0xBF80 : (u16)0);
      s += fabsf(f);
    }
    size_t di = i;
    if (ilv) {
      int e = i << 2;                 // element index
      int row = e >> 10, col = e & 1023;
      int dst = ((row >> 4) << 5) + ilv_add + (row & 15);
      di = ((size_t)dst << 8) + (col >> 2);
    }
    ((u16x4*)sgn)[di] = o;
  }
#pragma unroll
  for (int off = 32; off >= 1; off >>= 1) s += __shfl_xor(s, off);
  if ((t & 63) == 0) red[t >> 6] = s;
  __syncthreads();
  if (t == 0)
    partial[wi * 256 + blockIdx.x] = red[0] + red[1] + red[2] + red[3];
}

__global__ __launch_bounds__(256) void finalize_alpha(
    const float* __restrict__ partial, float* __restrict__ alphas) {
  __shared__ float red[4];
  int wi = blockIdx.x;  // 0..6
  float v = partial[wi * 256 + threadIdx.x];
#pragma unroll
  for (int off = 32; off >= 1; off >>= 1) v += __shfl_xor(v, off);
  if ((threadIdx.x & 63) == 0) red[threadIdx.x >> 6] = v;
  __syncthreads();
  if (threadIdx.x == 0)
    alphas[wi] = (red[0] + red[1] + red[2] + red[3]) *
                 (wi < 4 ? (1.f / 1048576.f) : (1.f / 4194304.f));
}

// ---------------------------------------------------------------------------
// RMSNorm + act_quant (group 64). One block per row of 1024.  (FFN branch)
// ---------------------------------------------------------------------------
__global__ __launch_bounds__(256) void rmsnorm_quant(
    const float* __restrict__ x, const float* __restrict__ g, u16* __restrict__ out) {
  __shared__ float red[4];
  const int row = blockIdx.x, t = threadIdx.x;
  f32x4 v = ((const f32x4*)(x + (size_t)row * 1024))[t];
  float ss = v[0] * v[0] + v[1] * v[1] + v[2] * v[2] + v[3] * v[3];
#pragma unroll
  for (int off = 32; off >= 1; off >>= 1) ss += __shfl_xor(ss, off);
  if ((t & 63) == 0) red[t >> 6] = ss;
  __syncthreads();
  float tot = red[0] + red[1] + red[2] + red[3];
  float rinv = rsqrtf(tot * (1.f / 1024.f) + 1e-6f);
  f32x4 gg = ((const f32x4*)g)[t];
  float n[4];
#pragma unroll
  for (int j = 0; j < 4; ++j) n[j] = v[j] * rinv * gg[j];
  float gm = fmaxf(fmaxf(fabsf(n[0]), fabsf(n[1])), fmaxf(fabsf(n[2]), fabsf(n[3])));
#pragma unroll
  for (int off = 1; off <= 8; off <<= 1) gm = fmaxf(gm, __shfl_xor(gm, off));
  float s = fmaxf(gm, 1e-5f) / 127.0f;
  u16x4 o;
#pragma unroll
  for (int j = 0; j < 4; ++j) {
    float q = fminf(fmaxf(rintf(n[j] / s), -127.f), 127.f) * s;
    o[j] = f2bf(q);
  }
  ((u16x4*)out)[(size_t)row * 256 + t] = o;
}

// ---------------------------------------------------------------------------
// V transpose: qkv[:,2048+h*64 .. +63] -> Vt[h][d][t]  ([16][64][4096] bf16).
// ---------------------------------------------------------------------------
__global__ __launch_bounds__(256) void transpose_v(
    const u16* __restrict__ qkv, u16* __restrict__ Vt) {
  __shared__ u16 T[64][65];
  const int tt = blockIdx.x, h = blockIdx.y, tid = threadIdx.x;
#pragma unroll
  for (int i = 0; i < 2; ++i) {
    int idx = i * 2048 + tid * 8;
    int trow = idx >> 6, dcol = idx & 63;
    u16x8 v = *(const u16x8*)(qkv + (size_t)(tt * 64 + trow) * 3072 + 2048 + h * 64 + dcol);
#pragma unroll
    for (int j = 0; j < 8; ++j) T[dcol + j][trow] = v[j];
  }
  __syncthreads();
#pragma unroll
  for (int i = 0; i < 2; ++i) {
    int idx = i * 2048 + tid * 8;
    int drow = idx >> 6, tcol = idx & 63;
    u16x8 v;
#pragma unroll
    for (int j = 0; j < 8; ++j) v[j] = T[drow][tcol + j];
    *(u16x8*)(Vt + ((size_t)h * 64 + drow) * 4096 + tt * 64 + tcol) = v;
  }
}

// ---------------------------------------------------------------------------
// GEMM: C[M,N] = alpha[bcol>>ashift] * (A[M,K] @ B[N,K]^T) (+res).
// BMx128 tile, BK=64, 4 waves, global_load_lds w=16, XOR swizzle.
// ---------------------------------------------------------------------------
template <bool RES, int BM>
__global__ __launch_bounds__(256) void gemm_bt(
    const u16* __restrict__ A, const u16* __restrict__ B,
    const float* __restrict__ alpha, int ashift, const float* __restrict__ res,
    void* __restrict__ Cout, int M, int N, int K) {
  constexpr int NI = (BM == 128) ? 4 : 2;
  constexpr int WNE = (BM == 128) ? 64 : 32;
  __shared__ u16 As[BM * 64];
  __shared__ u16 Bs[128 * 64];
  const int tid = threadIdx.x;
  const int l = tid & 63, w = tid >> 6;
  const int wm = (BM == 128) ? (w >> 1) : 0;
  const int wn = (BM == 128) ? (w & 1) : w;
  const int lr = l & 15, lg = l >> 4;
  const int xorv = (l & 7) << 4;
  const int brow = blockIdx.y * BM;
  const int bcol = blockIdx.x * 128;
  const int src_chunk = (l & 7) ^ (l >> 3);
  const int rl = w * 8 + (l >> 3);

  f32x4 acc[4][NI];
#pragma unroll
  for (int i = 0; i < 4; ++i)
#pragma unroll
    for (int j = 0; j < NI; ++j) acc[i][j] = (f32x4){0.f, 0.f, 0.f, 0.f};

  const char* Ag = (const char*)A;
  const char* Bg = (const char*)B;
  const int nkt = K >> 6;
  for (int kt = 0; kt < nkt; ++kt) {
    __syncthreads();
    const size_t kb = (size_t)kt * 128 + src_chunk * 16;
#pragma unroll
    for (int it = 0; it < BM / 32; ++it)
      gload16(Ag + (size_t)(brow + it * 32 + rl) * (size_t)(K * 2) + kb,
              &As[(it * 32 + w * 8) * 64]);
#pragma unroll
    for (int it = 0; it < 4; ++it)
      gload16(Bg + (size_t)(bcol + it * 32 + rl) * (size_t)(K * 2) + kb,
              &Bs[(it * 32 + w * 8) * 64]);
    __syncthreads();

    bf16x8 af[4][2], bfr[NI][2];
#pragma unroll
    for (int mi = 0; mi < 4; ++mi)
#pragma unroll
      for (int ks = 0; ks < 2; ++ks) {
        int row = wm * 64 + mi * 16 + lr;
        af[mi][ks] = *(const bf16x8*)((const char*)As + row * 128 + ((ks * 64 + lg * 16) ^ xorv));
      }
#pragma unroll
    for (int ni = 0; ni < NI; ++ni)
#pragma unroll
      for (int ks = 0; ks < 2; ++ks) {
        int row = wn * WNE + ni * 16 + lr;
        bfr[ni][ks] = *(const bf16x8*)((const char*)Bs + row * 128 + ((ks * 64 + lg * 16) ^ xorv));
      }
#pragma unroll
    for (int ks = 0; ks < 2; ++ks)
#pragma unroll
      for (int mi = 0; mi < 4; ++mi)
#pragma unroll
        for (int ni = 0; ni < NI; ++ni)
          acc[mi][ni] = __builtin_amdgcn_mfma_f32_16x16x32_bf16(
              af[mi][ks], bfr[ni][ks], acc[mi][ni], 0, 0, 0);
  }

  const float scale = alpha[bcol >> ashift];
#pragma unroll
  for (int mi = 0; mi < 4; ++mi)
#pragma unroll
    for (int ni = 0; ni < NI; ++ni)
#pragma unroll
      for (int r = 0; r < 4; ++r) {
        int row = brow + wm * 64 + mi * 16 + lg * 4 + r;
        int col = bcol + wn * WNE + ni * 16 + lr;
        float vv = acc[mi][ni][r] * scale;
        if (RES)
          ((float*)Cout)[(size_t)row * N + col] = res[(size_t)row * N + col] + vv;
        else
          ((u16*)Cout)[(size_t)row * N + col] = f2bf(vv);
      }
}

// ---------------------------------------------------------------------------
// Fat-wave GEMM: 256(M) x 128(N) tile, 4 waves, per-wave 128x64 output.
// 24 LDS reads / 64 MFMA per wave-iter. Used for the QKV projection.
// ---------------------------------------------------------------------------
template <bool RES>
__global__ __launch_bounds__(256, 2) void gemm_fat(
    const u16* __restrict__ A, const u16* __restrict__ B,
    const float* __restrict__ alpha, int ashift, const float* __restrict__ res,
    void* __restrict__ Cout, int M, int N, int K) {
  __shared__ u16 As[256 * 64];  // 32KB
  __shared__ u16 Bs[128 * 64];  // 16KB
  const int tid = threadIdx.x;
  const int l = tid & 63, w = tid >> 6;
  const int wm = w >> 1, wn = w & 1;
  const int lr = l & 15, lg = l >> 4;
  const int xorv = (l & 7) << 4;
  const int brow = blockIdx.y * 256;
  const int bcol = blockIdx.x * 128;
  const int src_chunk = (l & 7) ^ (l >> 3);
  const int rl = w * 8 + (l >> 3);

  f32x4 acc[8][4];
#pragma unroll
  for (int i = 0; i < 8; ++i)
#pragma unroll
    for (int j = 0; j < 4; ++j) acc[i][j] = (f32x4){0.f, 0.f, 0.f, 0.f};

  const int nkt = K >> 6;
  for (int kt = 0; kt < nkt; ++kt) {
    __syncthreads();
    const size_t kb = (size_t)kt * 128 + src_chunk * 16;
#pragma unroll
    for (int it = 0; it < 8; ++it)
      gload16((const char*)A + (size_t)(brow + it * 32 + rl) * (size_t)(K * 2) + kb,
              &As[(it * 32 + w * 8) * 64]);
#pragma unroll
    for (int it = 0; it < 4; ++it)
      gload16((const char*)B + (size_t)(bcol + it * 32 + rl) * (size_t)(K * 2) + kb,
              &Bs[(it * 32 + w * 8) * 64]);
    __syncthreads();

#pragma unroll
    for (int ks = 0; ks < 2; ++ks) {
      bf16x8 bfr[4];
#pragma unroll
      for (int ni = 0; ni < 4; ++ni)
        bfr[ni] = *(const bf16x8*)((const char*)Bs + (wn * 64 + ni * 16 + lr) * 128 +
                                   ((ks * 64 + lg * 16) ^ xorv));
#pragma unroll
      for (int mi = 0; mi < 8; ++mi) {
        bf16x8 af = *(const bf16x8*)((const char*)As + (wm * 128 + mi * 16 + lr) * 128 +
                                     ((ks * 64 + lg * 16) ^ xorv));
#pragma unroll
        for (int ni = 0; ni < 4; ++ni)
          acc[mi][ni] = __builtin_amdgcn_mfma_f32_16x16x32_bf16(
              af, bfr[ni], acc[mi][ni], 0, 0, 0);
      }
    }
  }

  const float scale = alpha[bcol >> ashift];
#pragma unroll
  for (int mi = 0; mi < 8; ++mi)
#pragma unroll
    for (int ni = 0; ni < 4; ++ni)
#pragma unroll
      for (int r = 0; r < 4; ++r) {
        int row = brow + wm * 128 + mi * 16 + lg * 4 + r;
        int col = bcol + wn * 64 + ni * 16 + lr;
        float vv = acc[mi][ni][r] * scale;
        if (RES)
          ((float*)Cout)[(size_t)row * N + col] = res[(size_t)row * N + col] + vv;
        else
          ((u16*)Cout)[(size_t)row * N + col] = f2bf(vv);
      }
}

// ---------------------------------------------------------------------------
// Fused FFN GEMM, fat-wave: tile 256(M) x 128(W12 rows = 64 z-cols),
// 4 waves, per-wave output 128x64 (acc 8x4). W12 fine-interleaved (16-row).
// ---------------------------------------------------------------------------
__global__ __launch_bounds__(256, 2) void gemm_ffn(
    const u16* __restrict__ A, const u16* __restrict__ B12,
    const float* __restrict__ alpha2, u16* __restrict__ zq) {
  __shared__ u16 As[256 * 64];  // 32KB
  __shared__ u16 Bs[128 * 64];  // 16KB
  const int tid = threadIdx.x;
  const int l = tid & 63, w = tid >> 6;
  const int wm = w >> 1, wn = w & 1;
  const int lr = l & 15, lg = l >> 4;
  const int xorv = (l & 7) << 4;
  const int brow = blockIdx.y * 256;
  const int bcol = blockIdx.x * 128;  // W12 row block = 64 z-cols
  const int src_chunk = (l & 7) ^ (l >> 3);
  const int rl = w * 8 + (l >> 3);

  f32x4 acc[8][4];
#pragma unroll
  for (int i = 0; i < 8; ++i)
#pragma unroll
    for (int j = 0; j < 4; ++j) acc[i][j] = (f32x4){0.f, 0.f, 0.f, 0.f};

  for (int kt = 0; kt < 16; ++kt) {
    __syncthreads();
    const size_t kb = (size_t)kt * 128 + src_chunk * 16;
#pragma unroll
    for (int it = 0; it < 8; ++it)
      gload16((const char*)A + (size_t)(brow + it * 32 + rl) * 2048 + kb,
              &As[(it * 32 + w * 8) * 64]);
#pragma unroll
    for (int it = 0; it < 4; ++it)
      gload16((const char*)B12 + (size_t)(bcol + it * 32 + rl) * 2048 + kb,
              &Bs[(it * 32 + w * 8) * 64]);
    __syncthreads();

#pragma unroll
    for (int ks = 0; ks < 2; ++ks) {
      bf16x8 bfr[4];
#pragma unroll
      for (int ni = 0; ni < 4; ++ni)
        bfr[ni] = *(const bf16x8*)((const char*)Bs + (wn * 64 + ni * 16 + lr) * 128 +
                                   ((ks * 64 + lg * 16) ^ xorv));
#pragma unroll
      for (int mi = 0; mi < 8; ++mi) {
        bf16x8 af = *(const bf16x8*)((const char*)As + (wm * 128 + mi * 16 + lr) * 128 +
                                     ((ks * 64 + lg * 16) ^ xorv));
#pragma unroll
        for (int ni = 0; ni < 4; ++ni)
          acc[mi][ni] = __builtin_amdgcn_mfma_f32_16x16x32_bf16(
              af, bfr[ni], acc[mi][ni], 0, 0, 0);
      }
    }
  }

  // ---- epilogue: z = silu(a1*y1)*(a2*y2) in-register ----
  const float a1 = alpha2[0], a2 = alpha2[1];
  const float L2E = 1.4426950408889634f;
  float zl[8][4], zh[8][4], rm[8][4];
#pragma unroll
  for (int mi = 0; mi < 8; ++mi)
#pragma unroll
    for (int r = 0; r < 4; ++r) {
      float y1 = acc[mi][0][r] * a1;
      zl[mi][r] = y1 / (1.f + fexp2(-L2E * y1)) * (acc[mi][1][r] * a2);
      float y3 = acc[mi][2][r] * a1;
      zh[mi][r] = y3 / (1.f + fexp2(-L2E * y3)) * (acc[mi][3][r] * a2);
      float g = fmaxf(fabsf(zl[mi][r]), fabsf(zh[mi][r]));
#pragma unroll
      for (int off = 1; off <= 8; off <<= 1) g = fmaxf(g, __shfl_xor(g, off));
      rm[mi][r] = g;  // this wave's 32-col max for the row
    }

  // cross-wave (wn pair: w and w^1 share wm) row-max via aliased staging LDS
  float* rmax = (float*)&As[0];  // [4][128] f32 = 2KB
  __syncthreads();               // all waves done reading staging
  if (lr == 0) {
#pragma unroll
    for (int mi = 0; mi < 8; ++mi)
#pragma unroll
      for (int r = 0; r < 4; ++r)
        rmax[w * 128 + mi * 16 + lg * 4 + r] = rm[mi][r];
  }
  __syncthreads();

#pragma unroll
  for (int mi = 0; mi < 8; ++mi)
#pragma unroll
    for (int r = 0; r < 4; ++r) {
      float g = fmaxf(rm[mi][r], rmax[(w ^ 1) * 128 + mi * 16 + lg * 4 + r]);
      float gmc = fmaxf(g, 1e-5f);
      float s = gmc * (1.f / 127.f);
      float inv = 127.f / gmc;
      int row = brow + wm * 128 + mi * 16 + lg * 4 + r;
      int zc = blockIdx.x * 64 + wn * 32 + lr;
      float q0 = fminf(fmaxf(rintf(zl[mi][r] * inv), -127.f), 127.f) * s;
      float q1 = fminf(fmaxf(rintf(zh[mi][r] * inv), -127.f), 127.f) * s;
      zq[(size_t)row * 4096 + zc] = f2bf(q0);
      zq[(size_t)row * 4096 + zc + 16] = f2bf(q1);
    }
}

// ---------------------------------------------------------------------------
// Causal flash attention + act_quant.  SWAPPED-OPERAND, BARRIER-FREE.
// K/V fragments read directly from global (L2-resident: 1MB/head).
// 4 waves x 16 q-rows; grid (16 heads, 64 q-tiles), qt = y<32?y:95-y
// (stride-256 round-robin -> every CU 130 wave-iter slots, now independent).
// Only LDS: per-wave 2KB P^T buffer (no barriers anywhere).
// ---------------------------------------------------------------------------
__global__ __launch_bounds__(256, 4) void attn_kernel(
    const u16* __restrict__ QKV, const u16* __restrict__ Vt, u16* __restrict__ Y) {
  __shared__ u16 Ps[4][16 * 64];  // per-wave P^T [q 16][token 64], 8KB

  const int tid = threadIdx.x;
  const int l = tid & 63, w = tid >> 6;
  const int lr = l & 15, lg = l >> 4;
  const int xorv = (l & 7) << 4;
  const int h = blockIdx.x;
  const int y = blockIdx.y;
  const int qt = (y < 32) ? y : (95 - y);  // 64-row q-tile index
  const float SC = 0.18033688f;            // 0.125 * log2(e)

  const int qrow0 = qt * 64 + w * 16;      // this wave's first q row
  const int nkt = qt + 1;

  bf16x8 qf[2];
#pragma unroll
  for (int ks = 0; ks < 2; ++ks)
    qf[ks] = ld8(QKV + (size_t)(qrow0 + lr) * 3072 + h * 64 + ks * 32 + lg * 8);

  // per-lane fragment base pointers (element units)
  const u16* Kb = QKV + 1024 + h * 64 + (size_t)lr * 3072 + lg * 8;
  const u16* Vb = Vt + ((size_t)(h * 64 + lr)) * 4096 + lg * 8;

  f32x4 O[4];  // O^T: lane holds O[q=lr][d = ni*16 + lg*4 + r]
#pragma unroll
  for (int ni = 0; ni < 4; ++ni) O[ni] = (f32x4){0.f, 0.f, 0.f, 0.f};
  float m_ = -3e38f, lsum = 0.f;

#pragma unroll 1
  for (int kt = 0; kt < nkt; ++kt) {
    // K fragments direct from L2: token = kt*64 + ni*16 + lr, d = ks*32+lg*8
    const u16* kp = Kb + (size_t)(kt * 64) * 3072;
    bf16x8 kf[4][2];
#pragma unroll
    for (int ni = 0; ni < 4; ++ni)
#pragma unroll
      for (int ks = 0; ks < 2; ++ks)
        kf[ni][ks] = ld8(kp + (size_t)(ni * 16) * 3072 + ks * 32);

    // S^T[ni] = mfma(K, Q)  (raw, unscaled)
    f32x4 S[4];
    __builtin_amdgcn_s_setprio(1);
#pragma unroll
    for (int ni = 0; ni < 4; ++ni) {
      S[ni] = (f32x4){0.f, 0.f, 0.f, 0.f};
#pragma unroll
      for (int ks = 0; ks < 2; ++ks)
        S[ni] = __builtin_amdgcn_mfma_f32_16x16x32_bf16(kf[ni][ks], qf[ks], S[ni], 0, 0, 0);
    }
    __builtin_amdgcn_s_setprio(0);

    // V fragments issued now -> latency hides under softmax
    const u16* vp = Vb + kt * 64;
    bf16x8 vf[4][2];
#pragma unroll
    for (int ni = 0; ni < 4; ++ni)
#pragma unroll
      for (int ks = 0; ks < 2; ++ks)
        vf[ni][ks] = ld8(vp + (size_t)(ni * 16) * 4096 + ks * 32);

    // causal mask on raw S (diag tile only)
    const int tb = kt * 64;
    if (tb + 63 > qrow0) {
#pragma unroll
      for (int ni = 0; ni < 4; ++ni)
#pragma unroll
        for (int r = 0; r < 4; ++r)
          if (tb + ni * 16 + lg * 4 + r > qrow0 + lr) S[ni][r] = -3e38f;
    }

    // online softmax (lane owns its q-row). Max on RAW S, scale folds to fma.
    float nm = -3e38f;
#pragma unroll
    for (int ni = 0; ni < 4; ++ni)
#pragma unroll
      for (int r = 0; r < 4; ++r) nm = fmaxf(nm, S[ni][r]);
    nm = fmaxf(nm, __shfl_xor(nm, 16));
    nm = fmaxf(nm, __shfl_xor(nm, 32));
    float nms = nm * SC;
    if (__ballot(nms > m_ + 8.f)) {  // T13 defer-rescale
      float mn = fmaxf(m_, nms);
      float fac = fexp2(m_ - mn);
      m_ = mn;
      lsum *= fac;
#pragma unroll
      for (int ni = 0; ni < 4; ++ni) O[ni] *= fac;
    }
    float rs = 0.f;
#pragma unroll
    for (int ni = 0; ni < 4; ++ni)
#pragma unroll
      for (int r = 0; r < 4; ++r) {
        float pv = fexp2(__builtin_fmaf(S[ni][r], SC, -m_));
        S[ni][r] = pv;
        rs += pv;
      }
    rs += __shfl_xor(rs, 16);
    rs += __shfl_xor(rs, 32);
    lsum += rs;

    // P^T -> per-wave LDS via cvt_pk, packed b64 (no cross-wave sync needed)
#pragma unroll
    for (int ni = 0; ni < 4; ++ni) {
      u32x2 pk;
      pk[0] = cvtpk(S[ni][0], S[ni][1]);
      pk[1] = cvtpk(S[ni][2], S[ni][3]);
      *(u32x2*)((char*)&Ps[w][0] + lr * 128 + ((ni * 32 + lg * 8) ^ xorv)) = pk;
    }
    bf16x8 pt[2];
#pragma unroll
    for (int ks = 0; ks < 2; ++ks)
      pt[ks] = *(const bf16x8*)((const char*)&Ps[w][0] + lr * 128 +
                                ((ks * 64 + lg * 16) ^ xorv));

    // O^T[ni] += mfma(V^T, P^T)
    __builtin_amdgcn_s_setprio(1);
#pragma unroll
    for (int ni = 0; ni < 4; ++ni)
#pragma unroll
      for (int ks = 0; ks < 2; ++ks)
        O[ni] = __builtin_amdgcn_mfma_f32_16x16x32_bf16(vf[ni][ks], pt[ks], O[ni], 0, 0, 0);
    __builtin_amdgcn_s_setprio(0);
  }

  // epilogue: normalize + act_quant (group of 64 = this head's dims)
  float rinv = 1.f / lsum;
  float o[4][4];
  float gm = 0.f;
#pragma unroll
  for (int ni = 0; ni < 4; ++ni)
#pragma unroll
    for (int r = 0; r < 4; ++r) {
      o[ni][r] = O[ni][r] * rinv;
      gm = fmaxf(gm, fabsf(o[ni][r]));
    }
  gm = fmaxf(gm, __shfl_xor(gm, 16));
  gm = fmaxf(gm, __shfl_xor(gm, 32));
  float gmc = fmaxf(gm, 1e-5f);
  float s = gmc * (1.f / 127.f);
  float inv = 127.f / gmc;
#pragma unroll
  for (int ni = 0; ni < 4; ++ni) {
    u16x4 ov;
#pragma unroll
    for (int r = 0; r < 4; ++r) {
      float q = fminf(fmaxf(rintf(o[ni][r] * inv), -127.f), 127.f) * s;
      ov[r] = f2bf(q);
    }
    *(u16x4*)(Y + (size_t)(qrow0 + lr) * 1024 + h * 64 + ni * 16 + lg * 4) = ov;
  }
}

// ---------------------------------------------------------------------------
extern "C" void kernel_launch(void* const* d_in, const int* in_sizes, int n_in,
                              void* d_out, int out_size, void* d_ws, size_t ws_size,
                              hipStream_t stream) {
  const float* x  = (const float*)d_in[0];
  const float* wq = (const float*)d_in[1];
  const float* wk = (const float*)d_in[2];
  const float* wv = (const float*)d_in[3];
  const float* wo = (const float*)d_in[4];
  const float* w1 = (const float*)d_in[5];
  const float* w2 = (const float*)d_in[6];
  const float* w3 = (const float*)d_in[7];
  const float* g1 = (const float*)d_in[8];
  const float* g2 = (const float*)d_in[9];

  char* ws = (char*)d_ws;
  const size_t MB = 1024 * 1024;
  u16* sgn   = (u16*)ws;
  u16* sWq   = (u16*)(ws + 0 * MB);
  u16* sWo   = (u16*)(ws + 6 * MB);
  u16* sW12  = (u16*)(ws + 8 * MB);    // fine-interleaved [8192,1024]
  u16* sW3   = (u16*)(ws + 24 * MB);
  float* partial = (float*)(ws + 32 * MB);
  float* alphas  = (float*)(ws + 32 * MB + 16384);
  u16* Vt    = (u16*)(ws + 33 * MB);   // dead before x1 written
  float* x1  = (float*)(ws + 33 * MB); // fp32 [4096,1024]
  u16* hq    = (u16*)(ws + 49 * MB);   // bf16 [4096,1024]
  u16* qkv   = (u16*)(ws + 57 * MB);   // bf16 [4096,3072]
  u16* yb    = (u16*)(ws + 81 * MB);   // bf16 [4096,1024]
  u16* zq    = (u16*)(ws + 57 * MB);   // bf16 [4096,4096] (qkv,yb dead)

  // weight prep + rmsnorm#1 (y==7) fused
  convert_sign_all<<<dim3(256, 8), 256, 0, stream>>>(wq, wk, wv, wo, w1, w2, w3,
                                                     sgn, partial, x, g1, hq);
  finalize_alpha<<<7, 256, 0, stream>>>(partial, alphas);

  // attention branch
  gemm_fat<false><<<dim3(24, 16), 256, 0, stream>>>(hq, sWq, alphas, 10, nullptr,
                                                    qkv, 4096, 3072, 1024);
  transpose_v<<<dim3(64, 16), 256, 0, stream>>>(qkv, Vt);
  attn_kernel<<<dim3(16, 64), 256, 0, stream>>>(qkv, Vt, yb);
  gemm_bt<true, 64><<<dim3(8, 64), 256, 0, stream>>>(yb, sWo, alphas + 3, 31, x,
                                                     x1, 4096, 1024, 1024);
  // FFN branch
  rmsnorm_quant<<<4096, 256, 0, stream>>>(x1, g2, hq);
  gemm_ffn<<<dim3(64, 16), 256, 0, stream>>>(hq, sW12, alphas + 4, zq);
  gemm_bt<true, 64><<<dim3(8, 64), 256, 0, stream>>>(zq, sW3, alphas + 6, 31, x1,
                                                     (float*)d_out, 4096, 1024, 4096);
}

// Round 13
// 371.123 us; speedup vs baseline: 1.2146x; 1.2146x over previous
//
#include <hip/hip_runtime.h>
#include <math.h>

// ============================================================================
// BitNet transformer block, MI355X (gfx950).  Round 13.
// R12 -> R13: attention = WAVE-PRIVATE STAGED, barrier-free.
// R12 failed (243us): direct-L2 K reads were uncoalesced gathers (16 lines
// per instr). R13 keeps coalesced global_load_lds staging but gives each
// wave its OWN KVBLK=32 double-buffered K/V tiles -> zero barriers, 8
// independent wave-chains/CU (R11: 2 lockstep chains). LDS 68KB/block,
// 2 blocks/CU. vmcnt is per-wave; ds_read->use ordering ensures buffer
// safety without syncs. Everything else = R11 state.
// ws layout (MB = 2^20): unchanged.
// ============================================================================

typedef unsigned short u16;
typedef unsigned int u32;
typedef __attribute__((ext_vector_type(2))) unsigned int u32x2;
typedef __attribute__((ext_vector_type(4))) float f32x4;
typedef __attribute__((ext_vector_type(4))) unsigned short u16x4;
typedef __attribute__((ext_vector_type(8))) unsigned short u16x8;
typedef __attribute__((ext_vector_type(8))) __bf16 bf16x8;

#define DEV static __device__ __forceinline__

DEV float bf2f(u16 u) { union { unsigned i; float f; } c; c.i = ((unsigned)u) << 16; return c.f; }
DEV u16 f2bf(float f) { __bf16 b = (__bf16)f; return __builtin_bit_cast(u16, b); }
DEV float fexp2(float x) { float r; asm("v_exp_f32 %0, %1" : "=v"(r) : "v"(x)); return r; }
DEV u32 cvtpk(float lo, float hi) {
  u32 r; asm("v_cvt_pk_bf16_f32 %0, %1, %2" : "=v"(r) : "v"(lo), "v"(hi)); return r;
}

DEV void gload16(const void* g, void* l) {
  __builtin_amdgcn_global_load_lds((__attribute__((address_space(1))) void*)g,
                                   (__attribute__((address_space(3))) void*)l,
                                   16, 0, 0);
}

// ---------------------------------------------------------------------------
// Weight prep: sign(w) -> bf16 {+1,-1,0}, block-partial |w| sums.
// wi 4/5 (w1/w2) interleave at 16-row granularity into one buffer at +8MB.
// wi==7: rmsnorm+act_quant of x (16 rows per block) - free overlap.
// ---------------------------------------------------------------------------
__global__ __launch_bounds__(256) void convert_sign_all(
    const float* __restrict__ w0, const float* __restrict__ w1,
    const float* __restrict__ w2, const float* __restrict__ w3,
    const float* __restrict__ w4, const float* __restrict__ w5,
    const float* __restrict__ w6, u16* __restrict__ sgn_base,
    float* __restrict__ partial,
    const float* __restrict__ x, const float* __restrict__ g1,
    u16* __restrict__ hq) {
  __shared__ float red[4];
  const int wi = blockIdx.y;
  const int t = threadIdx.x;

  if (wi == 7) {  // rmsnorm + act_quant for rows 16*bx .. +15
#pragma unroll 1
    for (int rr = 0; rr < 16; ++rr) {
      const int row = blockIdx.x * 16 + rr;
      f32x4 v = ((const f32x4*)(x + (size_t)row * 1024))[t];
      float ss = v[0] * v[0] + v[1] * v[1] + v[2] * v[2] + v[3] * v[3];
#pragma unroll
      for (int off = 32; off >= 1; off >>= 1) ss += __shfl_xor(ss, off);
      if ((t & 63) == 0) red[t >> 6] = ss;
      __syncthreads();
      float tot = red[0] + red[1] + red[2] + red[3];
      __syncthreads();
      float rinv = rsqrtf(tot * (1.f / 1024.f) + 1e-6f);
      f32x4 gg = ((const f32x4*)g1)[t];
      float n[4];
#pragma unroll
      for (int j = 0; j < 4; ++j) n[j] = v[j] * rinv * gg[j];
      float gm = fmaxf(fmaxf(fabsf(n[0]), fabsf(n[1])), fmaxf(fabsf(n[2]), fabsf(n[3])));
#pragma unroll
      for (int off = 1; off <= 8; off <<= 1) gm = fmaxf(gm, __shfl_xor(gm, off));
      float s = fmaxf(gm, 1e-5f) / 127.0f;
      u16x4 o;
#pragma unroll
      for (int j = 0; j < 4; ++j) {
        float q = fminf(fmaxf(rintf(n[j] / s), -127.f), 127.f) * s;
        o[j] = f2bf(q);
      }
      ((u16x4*)hq)[(size_t)row * 256 + t] = o;
    }
    return;
  }

  const float* srcs[7] = {w0, w1, w2, w3, w4, w5, w6};
  const size_t offs[7] = {0, 1048576, 2097152, 3145728, 4194304, 4194304, 12582912};
  const float* w = srcs[wi];
  u16* sgn = sgn_base + offs[wi];
  const int n4 = (wi < 4) ? 262144 : 1048576;
  const bool ilv = (wi == 4) || (wi == 5);
  const int ilv_add = (wi == 5) ? 16 : 0;

  float s = 0.f;
  for (int i = blockIdx.x * 256 + t; i < n4; i += 256 * 256) {
    f32x4 v = ((const f32x4*)w)[i];
    u16x4 o;
#pragma unroll
    for (int j = 0; j < 4; ++j) {
      float f = v[j];
      o[j] = f > 0.f ? (u16)0x3F80 : (f < 0.f ? (u16)0xBF80 : (u16)0);
      s += fabsf(f);
    }
    size_t di = i;
    if (ilv) {
      int e = i << 2;                 // element index
      int row = e >> 10, col = e & 1023;
      int dst = ((row >> 4) << 5) + ilv_add + (row & 15);
      di = ((size_t)dst << 8) + (col >> 2);
    }
    ((u16x4*)sgn)[di] = o;
  }
#pragma unroll
  for (int off = 32; off >= 1; off >>= 1) s += __shfl_xor(s, off);
  if ((t & 63) == 0) red[t >> 6] = s;
  __syncthreads();
  if (t == 0)
    partial[wi * 256 + blockIdx.x] = red[0] + red[1] + red[2] + red[3];
}

__global__ __launch_bounds__(256) void finalize_alpha(
    const float* __restrict__ partial, float* __restrict__ alphas) {
  __shared__ float red[4];
  int wi = blockIdx.x;  // 0..6
  float v = partial[wi * 256 + threadIdx.x];
#pragma unroll
  for (int off = 32; off >= 1; off >>= 1) v += __shfl_xor(v, off);
  if ((threadIdx.x & 63) == 0) red[threadIdx.x >> 6] = v;
  __syncthreads();
  if (threadIdx.x == 0)
    alphas[wi] = (red[0] + red[1] + red[2] + red[3]) *
                 (wi < 4 ? (1.f / 1048576.f) : (1.f / 4194304.f));
}

// ---------------------------------------------------------------------------
// RMSNorm + act_quant (group 64). One block per row of 1024.  (FFN branch)
// ---------------------------------------------------------------------------
__global__ __launch_bounds__(256) void rmsnorm_quant(
    const float* __restrict__ x, const float* __restrict__ g, u16* __restrict__ out) {
  __shared__ float red[4];
  const int row = blockIdx.x, t = threadIdx.x;
  f32x4 v = ((const f32x4*)(x + (size_t)row * 1024))[t];
  float ss = v[0] * v[0] + v[1] * v[1] + v[2] * v[2] + v[3] * v[3];
#pragma unroll
  for (int off = 32; off >= 1; off >>= 1) ss += __shfl_xor(ss, off);
  if ((t & 63) == 0) red[t >> 6] = ss;
  __syncthreads();
  float tot = red[0] + red[1] + red[2] + red[3];
  float rinv = rsqrtf(tot * (1.f / 1024.f) + 1e-6f);
  f32x4 gg = ((const f32x4*)g)[t];
  float n[4];
#pragma unroll
  for (int j = 0; j < 4; ++j) n[j] = v[j] * rinv * gg[j];
  float gm = fmaxf(fmaxf(fabsf(n[0]), fabsf(n[1])), fmaxf(fabsf(n[2]), fabsf(n[3])));
#pragma unroll
  for (int off = 1; off <= 8; off <<= 1) gm = fmaxf(gm, __shfl_xor(gm, off));
  float s = fmaxf(gm, 1e-5f) / 127.0f;
  u16x4 o;
#pragma unroll
  for (int j = 0; j < 4; ++j) {
    float q = fminf(fmaxf(rintf(n[j] / s), -127.f), 127.f) * s;
    o[j] = f2bf(q);
  }
  ((u16x4*)out)[(size_t)row * 256 + t] = o;
}

// ---------------------------------------------------------------------------
// V transpose: qkv[:,2048+h*64 .. +63] -> Vt[h][d][t]  ([16][64][4096] bf16).
// ---------------------------------------------------------------------------
__global__ __launch_bounds__(256) void transpose_v(
    const u16* __restrict__ qkv, u16* __restrict__ Vt) {
  __shared__ u16 T[64][65];
  const int tt = blockIdx.x, h = blockIdx.y, tid = threadIdx.x;
#pragma unroll
  for (int i = 0; i < 2; ++i) {
    int idx = i * 2048 + tid * 8;
    int trow = idx >> 6, dcol = idx & 63;
    u16x8 v = *(const u16x8*)(qkv + (size_t)(tt * 64 + trow) * 3072 + 2048 + h * 64 + dcol);
#pragma unroll
    for (int j = 0; j < 8; ++j) T[dcol + j][trow] = v[j];
  }
  __syncthreads();
#pragma unroll
  for (int i = 0; i < 2; ++i) {
    int idx = i * 2048 + tid * 8;
    int drow = idx >> 6, tcol = idx & 63;
    u16x8 v;
#pragma unroll
    for (int j = 0; j < 8; ++j) v[j] = T[drow][tcol + j];
    *(u16x8*)(Vt + ((size_t)h * 64 + drow) * 4096 + tt * 64 + tcol) = v;
  }
}

// ---------------------------------------------------------------------------
// GEMM: C[M,N] = alpha[bcol>>ashift] * (A[M,K] @ B[N,K]^T) (+res).
// BMx128 tile, BK=64, 4 waves, global_load_lds w=16, XOR swizzle.
// ---------------------------------------------------------------------------
template <bool RES, int BM>
__global__ __launch_bounds__(256) void gemm_bt(
    const u16* __restrict__ A, const u16* __restrict__ B,
    const float* __restrict__ alpha, int ashift, const float* __restrict__ res,
    void* __restrict__ Cout, int M, int N, int K) {
  constexpr int NI = (BM == 128) ? 4 : 2;
  constexpr int WNE = (BM == 128) ? 64 : 32;
  __shared__ u16 As[BM * 64];
  __shared__ u16 Bs[128 * 64];
  const int tid = threadIdx.x;
  const int l = tid & 63, w = tid >> 6;
  const int wm = (BM == 128) ? (w >> 1) : 0;
  const int wn = (BM == 128) ? (w & 1) : w;
  const int lr = l & 15, lg = l >> 4;
  const int xorv = (l & 7) << 4;
  const int brow = blockIdx.y * BM;
  const int bcol = blockIdx.x * 128;
  const int src_chunk = (l & 7) ^ (l >> 3);
  const int rl = w * 8 + (l >> 3);

  f32x4 acc[4][NI];
#pragma unroll
  for (int i = 0; i < 4; ++i)
#pragma unroll
    for (int j = 0; j < NI; ++j) acc[i][j] = (f32x4){0.f, 0.f, 0.f, 0.f};

  const char* Ag = (const char*)A;
  const char* Bg = (const char*)B;
  const int nkt = K >> 6;
  for (int kt = 0; kt < nkt; ++kt) {
    __syncthreads();
    const size_t kb = (size_t)kt * 128 + src_chunk * 16;
#pragma unroll
    for (int it = 0; it < BM / 32; ++it)
      gload16(Ag + (size_t)(brow + it * 32 + rl) * (size_t)(K * 2) + kb,
              &As[(it * 32 + w * 8) * 64]);
#pragma unroll
    for (int it = 0; it < 4; ++it)
      gload16(Bg + (size_t)(bcol + it * 32 + rl) * (size_t)(K * 2) + kb,
              &Bs[(it * 32 + w * 8) * 64]);
    __syncthreads();

    bf16x8 af[4][2], bfr[NI][2];
#pragma unroll
    for (int mi = 0; mi < 4; ++mi)
#pragma unroll
      for (int ks = 0; ks < 2; ++ks) {
        int row = wm * 64 + mi * 16 + lr;
        af[mi][ks] = *(const bf16x8*)((const char*)As + row * 128 + ((ks * 64 + lg * 16) ^ xorv));
      }
#pragma unroll
    for (int ni = 0; ni < NI; ++ni)
#pragma unroll
      for (int ks = 0; ks < 2; ++ks) {
        int row = wn * WNE + ni * 16 + lr;
        bfr[ni][ks] = *(const bf16x8*)((const char*)Bs + row * 128 + ((ks * 64 + lg * 16) ^ xorv));
      }
#pragma unroll
    for (int ks = 0; ks < 2; ++ks)
#pragma unroll
      for (int mi = 0; mi < 4; ++mi)
#pragma unroll
        for (int ni = 0; ni < NI; ++ni)
          acc[mi][ni] = __builtin_amdgcn_mfma_f32_16x16x32_bf16(
              af[mi][ks], bfr[ni][ks], acc[mi][ni], 0, 0, 0);
  }

  const float scale = alpha[bcol >> ashift];
#pragma unroll
  for (int mi = 0; mi < 4; ++mi)
#pragma unroll
    for (int ni = 0; ni < NI; ++ni)
#pragma unroll
      for (int r = 0; r < 4; ++r) {
        int row = brow + wm * 64 + mi * 16 + lg * 4 + r;
        int col = bcol + wn * WNE + ni * 16 + lr;
        float vv = acc[mi][ni][r] * scale;
        if (RES)
          ((float*)Cout)[(size_t)row * N + col] = res[(size_t)row * N + col] + vv;
        else
          ((u16*)Cout)[(size_t)row * N + col] = f2bf(vv);
      }
}

// ---------------------------------------------------------------------------
// Fat-wave GEMM: 256(M) x 128(N) tile, 4 waves, per-wave 128x64 output.
// 24 LDS reads / 64 MFMA per wave-iter. Used for the QKV projection.
// ---------------------------------------------------------------------------
template <bool RES>
__global__ __launch_bounds__(256, 2) void gemm_fat(
    const u16* __restrict__ A, const u16* __restrict__ B,
    const float* __restrict__ alpha, int ashift, const float* __restrict__ res,
    void* __restrict__ Cout, int M, int N, int K) {
  __shared__ u16 As[256 * 64];  // 32KB
  __shared__ u16 Bs[128 * 64];  // 16KB
  const int tid = threadIdx.x;
  const int l = tid & 63, w = tid >> 6;
  const int wm = w >> 1, wn = w & 1;
  const int lr = l & 15, lg = l >> 4;
  const int xorv = (l & 7) << 4;
  const int brow = blockIdx.y * 256;
  const int bcol = blockIdx.x * 128;
  const int src_chunk = (l & 7) ^ (l >> 3);
  const int rl = w * 8 + (l >> 3);

  f32x4 acc[8][4];
#pragma unroll
  for (int i = 0; i < 8; ++i)
#pragma unroll
    for (int j = 0; j < 4; ++j) acc[i][j] = (f32x4){0.f, 0.f, 0.f, 0.f};

  const int nkt = K >> 6;
  for (int kt = 0; kt < nkt; ++kt) {
    __syncthreads();
    const size_t kb = (size_t)kt * 128 + src_chunk * 16;
#pragma unroll
    for (int it = 0; it < 8; ++it)
      gload16((const char*)A + (size_t)(brow + it * 32 + rl) * (size_t)(K * 2) + kb,
              &As[(it * 32 + w * 8) * 64]);
#pragma unroll
    for (int it = 0; it < 4; ++it)
      gload16((const char*)B + (size_t)(bcol + it * 32 + rl) * (size_t)(K * 2) + kb,
              &Bs[(it * 32 + w * 8) * 64]);
    __syncthreads();

#pragma unroll
    for (int ks = 0; ks < 2; ++ks) {
      bf16x8 bfr[4];
#pragma unroll
      for (int ni = 0; ni < 4; ++ni)
        bfr[ni] = *(const bf16x8*)((const char*)Bs + (wn * 64 + ni * 16 + lr) * 128 +
                                   ((ks * 64 + lg * 16) ^ xorv));
#pragma unroll
      for (int mi = 0; mi < 8; ++mi) {
        bf16x8 af = *(const bf16x8*)((const char*)As + (wm * 128 + mi * 16 + lr) * 128 +
                                     ((ks * 64 + lg * 16) ^ xorv));
#pragma unroll
        for (int ni = 0; ni < 4; ++ni)
          acc[mi][ni] = __builtin_amdgcn_mfma_f32_16x16x32_bf16(
              af, bfr[ni], acc[mi][ni], 0, 0, 0);
      }
    }
  }

  const float scale = alpha[bcol >> ashift];
#pragma unroll
  for (int mi = 0; mi < 8; ++mi)
#pragma unroll
    for (int ni = 0; ni < 4; ++ni)
#pragma unroll
      for (int r = 0; r < 4; ++r) {
        int row = brow + wm * 128 + mi * 16 + lg * 4 + r;
        int col = bcol + wn * 64 + ni * 16 + lr;
        float vv = acc[mi][ni][r] * scale;
        if (RES)
          ((float*)Cout)[(size_t)row * N + col] = res[(size_t)row * N + col] + vv;
        else
          ((u16*)Cout)[(size_t)row * N + col] = f2bf(vv);
      }
}

// ---------------------------------------------------------------------------
// Fused FFN GEMM, fat-wave: tile 256(M) x 128(W12 rows = 64 z-cols),
// 4 waves, per-wave output 128x64 (acc 8x4). W12 fine-interleaved (16-row).
// ---------------------------------------------------------------------------
__global__ __launch_bounds__(256, 2) void gemm_ffn(
    const u16* __restrict__ A, const u16* __restrict__ B12,
    const float* __restrict__ alpha2, u16* __restrict__ zq) {
  __shared__ u16 As[256 * 64];  // 32KB
  __shared__ u16 Bs[128 * 64];  // 16KB
  const int tid = threadIdx.x;
  const int l = tid & 63, w = tid >> 6;
  const int wm = w >> 1, wn = w & 1;
  const int lr = l & 15, lg = l >> 4;
  const int xorv = (l & 7) << 4;
  const int brow = blockIdx.y * 256;
  const int bcol = blockIdx.x * 128;  // W12 row block = 64 z-cols
  const int src_chunk = (l & 7) ^ (l >> 3);
  const int rl = w * 8 + (l >> 3);

  f32x4 acc[8][4];
#pragma unroll
  for (int i = 0; i < 8; ++i)
#pragma unroll
    for (int j = 0; j < 4; ++j) acc[i][j] = (f32x4){0.f, 0.f, 0.f, 0.f};

  for (int kt = 0; kt < 16; ++kt) {
    __syncthreads();
    const size_t kb = (size_t)kt * 128 + src_chunk * 16;
#pragma unroll
    for (int it = 0; it < 8; ++it)
      gload16((const char*)A + (size_t)(brow + it * 32 + rl) * 2048 + kb,
              &As[(it * 32 + w * 8) * 64]);
#pragma unroll
    for (int it = 0; it < 4; ++it)
      gload16((const char*)B12 + (size_t)(bcol + it * 32 + rl) * 2048 + kb,
              &Bs[(it * 32 + w * 8) * 64]);
    __syncthreads();

#pragma unroll
    for (int ks = 0; ks < 2; ++ks) {
      bf16x8 bfr[4];
#pragma unroll
      for (int ni = 0; ni < 4; ++ni)
        bfr[ni] = *(const bf16x8*)((const char*)Bs + (wn * 64 + ni * 16 + lr) * 128 +
                                   ((ks * 64 + lg * 16) ^ xorv));
#pragma unroll
      for (int mi = 0; mi < 8; ++mi) {
        bf16x8 af = *(const bf16x8*)((const char*)As + (wm * 128 + mi * 16 + lr) * 128 +
                                     ((ks * 64 + lg * 16) ^ xorv));
#pragma unroll
        for (int ni = 0; ni < 4; ++ni)
          acc[mi][ni] = __builtin_amdgcn_mfma_f32_16x16x32_bf16(
              af, bfr[ni], acc[mi][ni], 0, 0, 0);
      }
    }
  }

  // ---- epilogue: z = silu(a1*y1)*(a2*y2) in-register ----
  const float a1 = alpha2[0], a2 = alpha2[1];
  const float L2E = 1.4426950408889634f;
  float zl[8][4], zh[8][4], rm[8][4];
#pragma unroll
  for (int mi = 0; mi < 8; ++mi)
#pragma unroll
    for (int r = 0; r < 4; ++r) {
      float y1 = acc[mi][0][r] * a1;
      zl[mi][r] = y1 / (1.f + fexp2(-L2E * y1)) * (acc[mi][1][r] * a2);
      float y3 = acc[mi][2][r] * a1;
      zh[mi][r] = y3 / (1.f + fexp2(-L2E * y3)) * (acc[mi][3][r] * a2);
      float g = fmaxf(fabsf(zl[mi][r]), fabsf(zh[mi][r]));
#pragma unroll
      for (int off = 1; off <= 8; off <<= 1) g = fmaxf(g, __shfl_xor(g, off));
      rm[mi][r] = g;  // this wave's 32-col max for the row
    }

  // cross-wave (wn pair: w and w^1 share wm) row-max via aliased staging LDS
  float* rmax = (float*)&As[0];  // [4][128] f32 = 2KB
  __syncthreads();               // all waves done reading staging
  if (lr == 0) {
#pragma unroll
    for (int mi = 0; mi < 8; ++mi)
#pragma unroll
      for (int r = 0; r < 4; ++r)
        rmax[w * 128 + mi * 16 + lg * 4 + r] = rm[mi][r];
  }
  __syncthreads();

#pragma unroll
  for (int mi = 0; mi < 8; ++mi)
#pragma unroll
    for (int r = 0; r < 4; ++r) {
      float g = fmaxf(rm[mi][r], rmax[(w ^ 1) * 128 + mi * 16 + lg * 4 + r]);
      float gmc = fmaxf(g, 1e-5f);
      float s = gmc * (1.f / 127.f);
      float inv = 127.f / gmc;
      int row = brow + wm * 128 + mi * 16 + lg * 4 + r;
      int zc = blockIdx.x * 64 + wn * 32 + lr;
      float q0 = fminf(fmaxf(rintf(zl[mi][r] * inv), -127.f), 127.f) * s;
      float q1 = fminf(fmaxf(rintf(zh[mi][r] * inv), -127.f), 127.f) * s;
      zq[(size_t)row * 4096 + zc] = f2bf(q0);
      zq[(size_t)row * 4096 + zc + 16] = f2bf(q1);
    }
}

// ---------------------------------------------------------------------------
// Causal flash attention + act_quant.  SWAPPED-OPERAND, WAVE-PRIVATE STAGED.
// Each wave owns 16 q-rows and stages its own KVBLK=32 K/V tiles via
// global_load_lds (coalesced) into private double buffers -> NO barriers,
// every wave an independent chain. Grid (16 heads, 64 q-tiles of 64 rows),
// qt = y<32?y:95-y (balanced). LDS 68KB -> 2 blocks/CU = 8 chains/CU.
// ---------------------------------------------------------------------------
__global__ __launch_bounds__(256) void attn_kernel(
    const u16* __restrict__ QKV, const u16* __restrict__ Vt, u16* __restrict__ Y) {
  __shared__ u16 Ks[4][2][32 * 64];  // per-wave [32 tok][64 d], 4KB each
  __shared__ u16 Vs[4][2][64 * 32];  // per-wave [64 d][32 tok], 4KB each
  __shared__ u16 Ps[4][16 * 32];     // per-wave P^T [16 q][32 tok], 1KB each

  const int tid = threadIdx.x;
  const int l = tid & 63, w = tid >> 6;
  const int lr = l & 15, lg = l >> 4;
  const int h = blockIdx.x;
  const int y = blockIdx.y;
  const int qt = (y < 32) ? y : (95 - y);  // 64-row q-tile index
  const float SC = 0.18033688f;            // 0.125 * log2(e)

  const int qrow0 = qt * 64 + w * 16;      // this wave's first q row
  const int nkt = 2 * qt + 1 + (w >> 1);   // per-wave causal tile count

  const int kchunk = (l & 7) ^ (l >> 3);        // K src swizzle (128B rows)
  const int vchunk = (l & 3) ^ ((l >> 2) & 3);  // V src swizzle (64B rows)

  bf16x8 qf[2];
#pragma unroll
  for (int ks = 0; ks < 2; ++ks)
    qf[ks] = __builtin_bit_cast(
        bf16x8, *(const u16x8*)(QKV + (size_t)(qrow0 + lr) * 3072 +
                                h * 64 + ks * 32 + lg * 8));

  f32x4 O[4];  // O^T: lane holds O[q=lr][d = ni*16 + lg*4 + r]
#pragma unroll
  for (int ni = 0; ni < 4; ++ni) O[ni] = (f32x4){0.f, 0.f, 0.f, 0.f};
  float m_ = -3e38f, lsum = 0.f;

  auto STAGE = [&](int buf, int kt) {
    // K tile: 32 tok x 128B, lane covers row l>>3, 4 instrs
#pragma unroll
    for (int it = 0; it < 4; ++it) {
      int krow = kt * 32 + it * 8 + (l >> 3);
      gload16((const char*)QKV + ((size_t)krow * 3072 + 1024 + h * 64) * 2 + kchunk * 16,
              &Ks[w][buf][(it * 8) * 64]);
    }
    // V tile: 64 d x 64B, lane covers row l>>2, 4 instrs
#pragma unroll
    for (int it = 0; it < 4; ++it) {
      int drow = it * 16 + (l >> 2);
      gload16((const char*)Vt + (((size_t)h * 64 + drow) * 4096 + kt * 32) * 2 + vchunk * 16,
              &Vs[w][buf][(it * 16) * 32]);
    }
  };

  STAGE(0, 0);
#pragma unroll 1
  for (int kt = 0; kt < nkt; ++kt) {
    const int cur = kt & 1;
    if (kt + 1 < nkt) {
      STAGE(cur ^ 1, kt + 1);
      asm volatile("s_waitcnt vmcnt(8)" ::: "memory");  // current tile's 8 done
    } else {
      asm volatile("s_waitcnt vmcnt(0)" ::: "memory");
    }
    __builtin_amdgcn_sched_barrier(0);

    const char* kbase = (const char*)&Ks[w][cur][0];
    const char* vbase = (const char*)&Vs[w][cur][0];

    // S^T[ni] = mfma(K, Q): tokens ni*16+lr, d = ks*32+lg*8
    f32x4 S[2];
    __builtin_amdgcn_s_setprio(1);
#pragma unroll
    for (int ni = 0; ni < 2; ++ni) {
      S[ni] = (f32x4){0.f, 0.f, 0.f, 0.f};
#pragma unroll
      for (int ks = 0; ks < 2; ++ks) {
        bf16x8 kf = *(const bf16x8*)(kbase + (ni * 16 + lr) * 128 +
                                     ((ks * 64 + lg * 16) ^ ((lr & 7) << 4)));
        S[ni] = __builtin_amdgcn_mfma_f32_16x16x32_bf16(kf, qf[ks], S[ni], 0, 0, 0);
      }
    }
    __builtin_amdgcn_s_setprio(0);

    // V fragments issued now (latency hides under softmax)
    bf16x8 vf[4];
#pragma unroll
    for (int ni = 0; ni < 4; ++ni)
      vf[ni] = *(const bf16x8*)(vbase + (ni * 16 + lr) * 64 +
                                ((lg * 16) ^ ((lr & 3) << 4)));

    // causal mask (raw S; only tiles reaching this wave's q range)
    const int tb = kt * 32;
    if (tb + 31 > qrow0) {
#pragma unroll
      for (int ni = 0; ni < 2; ++ni)
#pragma unroll
        for (int r = 0; r < 4; ++r)
          if (tb + ni * 16 + lg * 4 + r > qrow0 + lr) S[ni][r] = -3e38f;
    }

    // online softmax (lane owns q-row lr; row spans lanes lr, +16, +32, +48)
    float nm = fmaxf(fmaxf(S[0][0], S[0][1]), fmaxf(S[0][2], S[0][3]));
    nm = fmaxf(nm, fmaxf(fmaxf(S[1][0], S[1][1]), fmaxf(S[1][2], S[1][3])));
    nm = fmaxf(nm, __shfl_xor(nm, 16));
    nm = fmaxf(nm, __shfl_xor(nm, 32));
    float nms = nm * SC;
    if (__ballot(nms > m_ + 8.f)) {  // T13 defer-rescale
      float mn = fmaxf(m_, nms);
      float fac = fexp2(m_ - mn);
      m_ = mn;
      lsum *= fac;
#pragma unroll
      for (int ni = 0; ni < 4; ++ni) O[ni] *= fac;
    }
    float rs = 0.f;
#pragma unroll
    for (int ni = 0; ni < 2; ++ni)
#pragma unroll
      for (int r = 0; r < 4; ++r) {
        float pv = fexp2(__builtin_fmaf(S[ni][r], SC, -m_));
        S[ni][r] = pv;
        rs += pv;
      }
    rs += __shfl_xor(rs, 16);
    rs += __shfl_xor(rs, 32);
    lsum += rs;

    // P^T -> wave-private LDS [q=lr][tok], 8B packed writes (swizzled)
#pragma unroll
    for (int ni = 0; ni < 2; ++ni) {
      u32x2 pk;
      pk[0] = cvtpk(S[ni][0], S[ni][1]);
      pk[1] = cvtpk(S[ni][2], S[ni][3]);
      *(u32x2*)((char*)&Ps[w][0] + lr * 64 + ((ni * 32 + lg * 8) ^ ((lr & 3) << 4))) = pk;
    }
    bf16x8 pt = *(const bf16x8*)((const char*)&Ps[w][0] + lr * 64 +
                                 ((lg * 16) ^ ((lr & 3) << 4)));

    // O^T[ni] += mfma(V^T, P^T)  (K=32 -> single mfma per d-tile)
    __builtin_amdgcn_s_setprio(1);
#pragma unroll
    for (int ni = 0; ni < 4; ++ni)
      O[ni] = __builtin_amdgcn_mfma_f32_16x16x32_bf16(vf[ni], pt, O[ni], 0, 0, 0);
    __builtin_amdgcn_s_setprio(0);
  }

  // epilogue: normalize + act_quant (group of 64 = this head's dims)
  float rinv = 1.f / lsum;
  float o[4][4];
  float gm = 0.f;
#pragma unroll
  for (int ni = 0; ni < 4; ++ni)
#pragma unroll
    for (int r = 0; r < 4; ++r) {
      o[ni][r] = O[ni][r] * rinv;
      gm = fmaxf(gm, fabsf(o[ni][r]));
    }
  gm = fmaxf(gm, __shfl_xor(gm, 16));
  gm = fmaxf(gm, __shfl_xor(gm, 32));
  float gmc = fmaxf(gm, 1e-5f);
  float s = gmc * (1.f / 127.f);
  float inv = 127.f / gmc;
#pragma unroll
  for (int ni = 0; ni < 4; ++ni) {
    u16x4 ov;
#pragma unroll
    for (int r = 0; r < 4; ++r) {
      float q = fminf(fmaxf(rintf(o[ni][r] * inv), -127.f), 127.f) * s;
      ov[r] = f2bf(q);
    }
    *(u16x4*)(Y + (size_t)(qrow0 + lr) * 1024 + h * 64 + ni * 16 + lg * 4) = ov;
  }
}

// ---------------------------------------------------------------------------
extern "C" void kernel_launch(void* const* d_in, const int* in_sizes, int n_in,
                              void* d_out, int out_size, void* d_ws, size_t ws_size,
                              hipStream_t stream) {
  const float* x  = (const float*)d_in[0];
  const float* wq = (const float*)d_in[1];
  const float* wk = (const float*)d_in[2];
  const float* wv = (const float*)d_in[3];
  const float* wo = (const float*)d_in[4];
  const float* w1 = (const float*)d_in[5];
  const float* w2 = (const float*)d_in[6];
  const float* w3 = (const float*)d_in[7];
  const float* g1 = (const float*)d_in[8];
  const float* g2 = (const float*)d_in[9];

  char* ws = (char*)d_ws;
  const size_t MB = 1024 * 1024;
  u16* sgn   = (u16*)ws;
  u16* sWq   = (u16*)(ws + 0 * MB);
  u16* sWo   = (u16*)(ws + 6 * MB);
  u16* sW12  = (u16*)(ws + 8 * MB);    // fine-interleaved [8192,1024]
  u16* sW3   = (u16*)(ws + 24 * MB);
  float* partial = (float*)(ws + 32 * MB);
  float* alphas  = (float*)(ws + 32 * MB + 16384);
  u16* Vt    = (u16*)(ws + 33 * MB);   // dead before x1 written
  float* x1  = (float*)(ws + 33 * MB); // fp32 [4096,1024]
  u16* hq    = (u16*)(ws + 49 * MB);   // bf16 [4096,1024]
  u16* qkv   = (u16*)(ws + 57 * MB);   // bf16 [4096,3072]
  u16* yb    = (u16*)(ws + 81 * MB);   // bf16 [4096,1024]
  u16* zq    = (u16*)(ws + 57 * MB);   // bf16 [4096,4096] (qkv,yb dead)

  // weight prep + rmsnorm#1 (y==7) fused
  convert_sign_all<<<dim3(256, 8), 256, 0, stream>>>(wq, wk, wv, wo, w1, w2, w3,
                                                     sgn, partial, x, g1, hq);
  finalize_alpha<<<7, 256, 0, stream>>>(partial, alphas);

  // attention branch
  gemm_fat<false><<<dim3(24, 16), 256, 0, stream>>>(hq, sWq, alphas, 10, nullptr,
                                                    qkv, 4096, 3072, 1024);
  transpose_v<<<dim3(64, 16), 256, 0, stream>>>(qkv, Vt);
  attn_kernel<<<dim3(16, 64), 256, 0, stream>>>(qkv, Vt, yb);
  gemm_bt<true, 64><<<dim3(8, 64), 256, 0, stream>>>(yb, sWo, alphas + 3, 31, x,
                                                     x1, 4096, 1024, 1024);
  // FFN branch
  rmsnorm_quant<<<4096, 256, 0, stream>>>(x1, g2, hq);
  gemm_ffn<<<dim3(64, 16), 256, 0, stream>>>(hq, sW12, alphas + 4, zq);
  gemm_bt<true, 64><<<dim3(8, 64), 256, 0, stream>>>(zq, sW3, alphas + 6, 31, x1,
                                                     (float*)d_out, 4096, 1024, 4096);
}

// Round 14
// 333.013 us; speedup vs baseline: 1.3536x; 1.1144x over previous
//
#include <hip/hip_runtime.h>
#include <math.h>

// ============================================================================
// BitNet transformer block, MI355X (gfx950).  Round 14.
// R13 -> R14: attention reverted to the proven block-staged swapped form
// (R11) and widened: QBLK=128 with 4 waves x 32 q-rows (2 Q B-frags/wave).
// Model (R10/R11 data): attn is LDS-PIPE THROUGHPUT bound; K/V fragment
// reads are per-wave-invariant in q, so 2x q-rows/wave cuts LDS ops per
// q-token 31% and halves barriers/q. KVBLK=64 dbuf staging, R11 VALU diet.
// Grid (16,32), qt = y<16?y:47-y -> every CU 68 balanced slots. LDS 48KB.
// ws layout (MB = 2^20): unchanged.
// ============================================================================

typedef unsigned short u16;
typedef unsigned int u32;
typedef __attribute__((ext_vector_type(2))) unsigned int u32x2;
typedef __attribute__((ext_vector_type(4))) float f32x4;
typedef __attribute__((ext_vector_type(4))) unsigned short u16x4;
typedef __attribute__((ext_vector_type(8))) unsigned short u16x8;
typedef __attribute__((ext_vector_type(8))) __bf16 bf16x8;

#define DEV static __device__ __forceinline__

DEV float bf2f(u16 u) { union { unsigned i; float f; } c; c.i = ((unsigned)u) << 16; return c.f; }
DEV u16 f2bf(float f) { __bf16 b = (__bf16)f; return __builtin_bit_cast(u16, b); }
DEV float fexp2(float x) { float r; asm("v_exp_f32 %0, %1" : "=v"(r) : "v"(x)); return r; }
DEV u32 cvtpk(float lo, float hi) {
  u32 r; asm("v_cvt_pk_bf16_f32 %0, %1, %2" : "=v"(r) : "v"(lo), "v"(hi)); return r;
}

DEV void gload16(const void* g, void* l) {
  __builtin_amdgcn_global_load_lds((__attribute__((address_space(1))) void*)g,
                                   (__attribute__((address_space(3))) void*)l,
                                   16, 0, 0);
}

// ---------------------------------------------------------------------------
// Weight prep: sign(w) -> bf16 {+1,-1,0}, block-partial |w| sums.
// wi 4/5 (w1/w2) interleave at 16-row granularity into one buffer at +8MB.
// wi==7: rmsnorm+act_quant of x (16 rows per block) - free overlap.
// ---------------------------------------------------------------------------
__global__ __launch_bounds__(256) void convert_sign_all(
    const float* __restrict__ w0, const float* __restrict__ w1,
    const float* __restrict__ w2, const float* __restrict__ w3,
    const float* __restrict__ w4, const float* __restrict__ w5,
    const float* __restrict__ w6, u16* __restrict__ sgn_base,
    float* __restrict__ partial,
    const float* __restrict__ x, const float* __restrict__ g1,
    u16* __restrict__ hq) {
  __shared__ float red[4];
  const int wi = blockIdx.y;
  const int t = threadIdx.x;

  if (wi == 7) {  // rmsnorm + act_quant for rows 16*bx .. +15
#pragma unroll 1
    for (int rr = 0; rr < 16; ++rr) {
      const int row = blockIdx.x * 16 + rr;
      f32x4 v = ((const f32x4*)(x + (size_t)row * 1024))[t];
      float ss = v[0] * v[0] + v[1] * v[1] + v[2] * v[2] + v[3] * v[3];
#pragma unroll
      for (int off = 32; off >= 1; off >>= 1) ss += __shfl_xor(ss, off);
      if ((t & 63) == 0) red[t >> 6] = ss;
      __syncthreads();
      float tot = red[0] + red[1] + red[2] + red[3];
      __syncthreads();
      float rinv = rsqrtf(tot * (1.f / 1024.f) + 1e-6f);
      f32x4 gg = ((const f32x4*)g1)[t];
      float n[4];
#pragma unroll
      for (int j = 0; j < 4; ++j) n[j] = v[j] * rinv * gg[j];
      float gm = fmaxf(fmaxf(fabsf(n[0]), fabsf(n[1])), fmaxf(fabsf(n[2]), fabsf(n[3])));
#pragma unroll
      for (int off = 1; off <= 8; off <<= 1) gm = fmaxf(gm, __shfl_xor(gm, off));
      float s = fmaxf(gm, 1e-5f) / 127.0f;
      u16x4 o;
#pragma unroll
      for (int j = 0; j < 4; ++j) {
        float q = fminf(fmaxf(rintf(n[j] / s), -127.f), 127.f) * s;
        o[j] = f2bf(q);
      }
      ((u16x4*)hq)[(size_t)row * 256 + t] = o;
    }
    return;
  }

  const float* srcs[7] = {w0, w1, w2, w3, w4, w5, w6};
  const size_t offs[7] = {0, 1048576, 2097152, 3145728, 4194304, 4194304, 12582912};
  const float* w = srcs[wi];
  u16* sgn = sgn_base + offs[wi];
  const int n4 = (wi < 4) ? 262144 : 1048576;
  const bool ilv = (wi == 4) || (wi == 5);
  const int ilv_add = (wi == 5) ? 16 : 0;

  float s = 0.f;
  for (int i = blockIdx.x * 256 + t; i < n4; i += 256 * 256) {
    f32x4 v = ((const f32x4*)w)[i];
    u16x4 o;
#pragma unroll
    for (int j = 0; j < 4; ++j) {
      float f = v[j];
      o[j] = f > 0.f ? (u16)0x3F80 : (f < 0.f ? (u16)0xBF80 : (u16)0);
      s += fabsf(f);
    }
    size_t di = i;
    if (ilv) {
      int e = i << 2;                 // element index
      int row = e >> 10, col = e & 1023;
      int dst = ((row >> 4) << 5) + ilv_add + (row & 15);
      di = ((size_t)dst << 8) + (col >> 2);
    }
    ((u16x4*)sgn)[di] = o;
  }
#pragma unroll
  for (int off = 32; off >= 1; off >>= 1) s += __shfl_xor(s, off);
  if ((t & 63) == 0) red[t >> 6] = s;
  __syncthreads();
  if (t == 0)
    partial[wi * 256 + blockIdx.x] = red[0] + red[1] + red[2] + red[3];
}

__global__ __launch_bounds__(256) void finalize_alpha(
    const float* __restrict__ partial, float* __restrict__ alphas) {
  __shared__ float red[4];
  int wi = blockIdx.x;  // 0..6
  float v = partial[wi * 256 + threadIdx.x];
#pragma unroll
  for (int off = 32; off >= 1; off >>= 1) v += __shfl_xor(v, off);
  if ((threadIdx.x & 63) == 0) red[threadIdx.x >> 6] = v;
  __syncthreads();
  if (threadIdx.x == 0)
    alphas[wi] = (red[0] + red[1] + red[2] + red[3]) *
                 (wi < 4 ? (1.f / 1048576.f) : (1.f / 4194304.f));
}

// ---------------------------------------------------------------------------
// RMSNorm + act_quant (group 64). One block per row of 1024.  (FFN branch)
// ---------------------------------------------------------------------------
__global__ __launch_bounds__(256) void rmsnorm_quant(
    const float* __restrict__ x, const float* __restrict__ g, u16* __restrict__ out) {
  __shared__ float red[4];
  const int row = blockIdx.x, t = threadIdx.x;
  f32x4 v = ((const f32x4*)(x + (size_t)row * 1024))[t];
  float ss = v[0] * v[0] + v[1] * v[1] + v[2] * v[2] + v[3] * v[3];
#pragma unroll
  for (int off = 32; off >= 1; off >>= 1) ss += __shfl_xor(ss, off);
  if ((t & 63) == 0) red[t >> 6] = ss;
  __syncthreads();
  float tot = red[0] + red[1] + red[2] + red[3];
  float rinv = rsqrtf(tot * (1.f / 1024.f) + 1e-6f);
  f32x4 gg = ((const f32x4*)g)[t];
  float n[4];
#pragma unroll
  for (int j = 0; j < 4; ++j) n[j] = v[j] * rinv * gg[j];
  float gm = fmaxf(fmaxf(fabsf(n[0]), fabsf(n[1])), fmaxf(fabsf(n[2]), fabsf(n[3])));
#pragma unroll
  for (int off = 1; off <= 8; off <<= 1) gm = fmaxf(gm, __shfl_xor(gm, off));
  float s = fmaxf(gm, 1e-5f) / 127.0f;
  u16x4 o;
#pragma unroll
  for (int j = 0; j < 4; ++j) {
    float q = fminf(fmaxf(rintf(n[j] / s), -127.f), 127.f) * s;
    o[j] = f2bf(q);
  }
  ((u16x4*)out)[(size_t)row * 256 + t] = o;
}

// ---------------------------------------------------------------------------
// V transpose: qkv[:,2048+h*64 .. +63] -> Vt[h][d][t]  ([16][64][4096] bf16).
// ---------------------------------------------------------------------------
__global__ __launch_bounds__(256) void transpose_v(
    const u16* __restrict__ qkv, u16* __restrict__ Vt) {
  __shared__ u16 T[64][65];
  const int tt = blockIdx.x, h = blockIdx.y, tid = threadIdx.x;
#pragma unroll
  for (int i = 0; i < 2; ++i) {
    int idx = i * 2048 + tid * 8;
    int trow = idx >> 6, dcol = idx & 63;
    u16x8 v = *(const u16x8*)(qkv + (size_t)(tt * 64 + trow) * 3072 + 2048 + h * 64 + dcol);
#pragma unroll
    for (int j = 0; j < 8; ++j) T[dcol + j][trow] = v[j];
  }
  __syncthreads();
#pragma unroll
  for (int i = 0; i < 2; ++i) {
    int idx = i * 2048 + tid * 8;
    int drow = idx >> 6, tcol = idx & 63;
    u16x8 v;
#pragma unroll
    for (int j = 0; j < 8; ++j) v[j] = T[drow][tcol + j];
    *(u16x8*)(Vt + ((size_t)h * 64 + drow) * 4096 + tt * 64 + tcol) = v;
  }
}

// ---------------------------------------------------------------------------
// GEMM: C[M,N] = alpha[bcol>>ashift] * (A[M,K] @ B[N,K]^T) (+res).
// BMx128 tile, BK=64, 4 waves, global_load_lds w=16, XOR swizzle.
// ---------------------------------------------------------------------------
template <bool RES, int BM>
__global__ __launch_bounds__(256) void gemm_bt(
    const u16* __restrict__ A, const u16* __restrict__ B,
    const float* __restrict__ alpha, int ashift, const float* __restrict__ res,
    void* __restrict__ Cout, int M, int N, int K) {
  constexpr int NI = (BM == 128) ? 4 : 2;
  constexpr int WNE = (BM == 128) ? 64 : 32;
  __shared__ u16 As[BM * 64];
  __shared__ u16 Bs[128 * 64];
  const int tid = threadIdx.x;
  const int l = tid & 63, w = tid >> 6;
  const int wm = (BM == 128) ? (w >> 1) : 0;
  const int wn = (BM == 128) ? (w & 1) : w;
  const int lr = l & 15, lg = l >> 4;
  const int xorv = (l & 7) << 4;
  const int brow = blockIdx.y * BM;
  const int bcol = blockIdx.x * 128;
  const int src_chunk = (l & 7) ^ (l >> 3);
  const int rl = w * 8 + (l >> 3);

  f32x4 acc[4][NI];
#pragma unroll
  for (int i = 0; i < 4; ++i)
#pragma unroll
    for (int j = 0; j < NI; ++j) acc[i][j] = (f32x4){0.f, 0.f, 0.f, 0.f};

  const char* Ag = (const char*)A;
  const char* Bg = (const char*)B;
  const int nkt = K >> 6;
  for (int kt = 0; kt < nkt; ++kt) {
    __syncthreads();
    const size_t kb = (size_t)kt * 128 + src_chunk * 16;
#pragma unroll
    for (int it = 0; it < BM / 32; ++it)
      gload16(Ag + (size_t)(brow + it * 32 + rl) * (size_t)(K * 2) + kb,
              &As[(it * 32 + w * 8) * 64]);
#pragma unroll
    for (int it = 0; it < 4; ++it)
      gload16(Bg + (size_t)(bcol + it * 32 + rl) * (size_t)(K * 2) + kb,
              &Bs[(it * 32 + w * 8) * 64]);
    __syncthreads();

    bf16x8 af[4][2], bfr[NI][2];
#pragma unroll
    for (int mi = 0; mi < 4; ++mi)
#pragma unroll
      for (int ks = 0; ks < 2; ++ks) {
        int row = wm * 64 + mi * 16 + lr;
        af[mi][ks] = *(const bf16x8*)((const char*)As + row * 128 + ((ks * 64 + lg * 16) ^ xorv));
      }
#pragma unroll
    for (int ni = 0; ni < NI; ++ni)
#pragma unroll
      for (int ks = 0; ks < 2; ++ks) {
        int row = wn * WNE + ni * 16 + lr;
        bfr[ni][ks] = *(const bf16x8*)((const char*)Bs + row * 128 + ((ks * 64 + lg * 16) ^ xorv));
      }
#pragma unroll
    for (int ks = 0; ks < 2; ++ks)
#pragma unroll
      for (int mi = 0; mi < 4; ++mi)
#pragma unroll
        for (int ni = 0; ni < NI; ++ni)
          acc[mi][ni] = __builtin_amdgcn_mfma_f32_16x16x32_bf16(
              af[mi][ks], bfr[ni][ks], acc[mi][ni], 0, 0, 0);
  }

  const float scale = alpha[bcol >> ashift];
#pragma unroll
  for (int mi = 0; mi < 4; ++mi)
#pragma unroll
    for (int ni = 0; ni < NI; ++ni)
#pragma unroll
      for (int r = 0; r < 4; ++r) {
        int row = brow + wm * 64 + mi * 16 + lg * 4 + r;
        int col = bcol + wn * WNE + ni * 16 + lr;
        float vv = acc[mi][ni][r] * scale;
        if (RES)
          ((float*)Cout)[(size_t)row * N + col] = res[(size_t)row * N + col] + vv;
        else
          ((u16*)Cout)[(size_t)row * N + col] = f2bf(vv);
      }
}

// ---------------------------------------------------------------------------
// Fat-wave GEMM: 256(M) x 128(N) tile, 4 waves, per-wave 128x64 output.
// 24 LDS reads / 64 MFMA per wave-iter. Used for the QKV projection.
// ---------------------------------------------------------------------------
template <bool RES>
__global__ __launch_bounds__(256, 2) void gemm_fat(
    const u16* __restrict__ A, const u16* __restrict__ B,
    const float* __restrict__ alpha, int ashift, const float* __restrict__ res,
    void* __restrict__ Cout, int M, int N, int K) {
  __shared__ u16 As[256 * 64];  // 32KB
  __shared__ u16 Bs[128 * 64];  // 16KB
  const int tid = threadIdx.x;
  const int l = tid & 63, w = tid >> 6;
  const int wm = w >> 1, wn = w & 1;
  const int lr = l & 15, lg = l >> 4;
  const int xorv = (l & 7) << 4;
  const int brow = blockIdx.y * 256;
  const int bcol = blockIdx.x * 128;
  const int src_chunk = (l & 7) ^ (l >> 3);
  const int rl = w * 8 + (l >> 3);

  f32x4 acc[8][4];
#pragma unroll
  for (int i = 0; i < 8; ++i)
#pragma unroll
    for (int j = 0; j < 4; ++j) acc[i][j] = (f32x4){0.f, 0.f, 0.f, 0.f};

  const int nkt = K >> 6;
  for (int kt = 0; kt < nkt; ++kt) {
    __syncthreads();
    const size_t kb = (size_t)kt * 128 + src_chunk * 16;
#pragma unroll
    for (int it = 0; it < 8; ++it)
      gload16((const char*)A + (size_t)(brow + it * 32 + rl) * (size_t)(K * 2) + kb,
              &As[(it * 32 + w * 8) * 64]);
#pragma unroll
    for (int it = 0; it < 4; ++it)
      gload16((const char*)B + (size_t)(bcol + it * 32 + rl) * (size_t)(K * 2) + kb,
              &Bs[(it * 32 + w * 8) * 64]);
    __syncthreads();

#pragma unroll
    for (int ks = 0; ks < 2; ++ks) {
      bf16x8 bfr[4];
#pragma unroll
      for (int ni = 0; ni < 4; ++ni)
        bfr[ni] = *(const bf16x8*)((const char*)Bs + (wn * 64 + ni * 16 + lr) * 128 +
                                   ((ks * 64 + lg * 16) ^ xorv));
#pragma unroll
      for (int mi = 0; mi < 8; ++mi) {
        bf16x8 af = *(const bf16x8*)((const char*)As + (wm * 128 + mi * 16 + lr) * 128 +
                                     ((ks * 64 + lg * 16) ^ xorv));
#pragma unroll
        for (int ni = 0; ni < 4; ++ni)
          acc[mi][ni] = __builtin_amdgcn_mfma_f32_16x16x32_bf16(
              af, bfr[ni], acc[mi][ni], 0, 0, 0);
      }
    }
  }

  const float scale = alpha[bcol >> ashift];
#pragma unroll
  for (int mi = 0; mi < 8; ++mi)
#pragma unroll
    for (int ni = 0; ni < 4; ++ni)
#pragma unroll
      for (int r = 0; r < 4; ++r) {
        int row = brow + wm * 128 + mi * 16 + lg * 4 + r;
        int col = bcol + wn * 64 + ni * 16 + lr;
        float vv = acc[mi][ni][r] * scale;
        if (RES)
          ((float*)Cout)[(size_t)row * N + col] = res[(size_t)row * N + col] + vv;
        else
          ((u16*)Cout)[(size_t)row * N + col] = f2bf(vv);
      }
}

// ---------------------------------------------------------------------------
// Fused FFN GEMM, fat-wave: tile 256(M) x 128(W12 rows = 64 z-cols),
// 4 waves, per-wave output 128x64 (acc 8x4). W12 fine-interleaved (16-row).
// ---------------------------------------------------------------------------
__global__ __launch_bounds__(256, 2) void gemm_ffn(
    const u16* __restrict__ A, const u16* __restrict__ B12,
    const float* __restrict__ alpha2, u16* __restrict__ zq) {
  __shared__ u16 As[256 * 64];  // 32KB
  __shared__ u16 Bs[128 * 64];  // 16KB
  const int tid = threadIdx.x;
  const int l = tid & 63, w = tid >> 6;
  const int wm = w >> 1, wn = w & 1;
  const int lr = l & 15, lg = l >> 4;
  const int xorv = (l & 7) << 4;
  const int brow = blockIdx.y * 256;
  const int bcol = blockIdx.x * 128;  // W12 row block = 64 z-cols
  const int src_chunk = (l & 7) ^ (l >> 3);
  const int rl = w * 8 + (l >> 3);

  f32x4 acc[8][4];
#pragma unroll
  for (int i = 0; i < 8; ++i)
#pragma unroll
    for (int j = 0; j < 4; ++j) acc[i][j] = (f32x4){0.f, 0.f, 0.f, 0.f};

  for (int kt = 0; kt < 16; ++kt) {
    __syncthreads();
    const size_t kb = (size_t)kt * 128 + src_chunk * 16;
#pragma unroll
    for (int it = 0; it < 8; ++it)
      gload16((const char*)A + (size_t)(brow + it * 32 + rl) * 2048 + kb,
              &As[(it * 32 + w * 8) * 64]);
#pragma unroll
    for (int it = 0; it < 4; ++it)
      gload16((const char*)B12 + (size_t)(bcol + it * 32 + rl) * 2048 + kb,
              &Bs[(it * 32 + w * 8) * 64]);
    __syncthreads();

#pragma unroll
    for (int ks = 0; ks < 2; ++ks) {
      bf16x8 bfr[4];
#pragma unroll
      for (int ni = 0; ni < 4; ++ni)
        bfr[ni] = *(const bf16x8*)((const char*)Bs + (wn * 64 + ni * 16 + lr) * 128 +
                                   ((ks * 64 + lg * 16) ^ xorv));
#pragma unroll
      for (int mi = 0; mi < 8; ++mi) {
        bf16x8 af = *(const bf16x8*)((const char*)As + (wm * 128 + mi * 16 + lr) * 128 +
                                     ((ks * 64 + lg * 16) ^ xorv));
#pragma unroll
        for (int ni = 0; ni < 4; ++ni)
          acc[mi][ni] = __builtin_amdgcn_mfma_f32_16x16x32_bf16(
              af, bfr[ni], acc[mi][ni], 0, 0, 0);
      }
    }
  }

  // ---- epilogue: z = silu(a1*y1)*(a2*y2) in-register ----
  const float a1 = alpha2[0], a2 = alpha2[1];
  const float L2E = 1.4426950408889634f;
  float zl[8][4], zh[8][4], rm[8][4];
#pragma unroll
  for (int mi = 0; mi < 8; ++mi)
#pragma unroll
    for (int r = 0; r < 4; ++r) {
      float y1 = acc[mi][0][r] * a1;
      zl[mi][r] = y1 / (1.f + fexp2(-L2E * y1)) * (acc[mi][1][r] * a2);
      float y3 = acc[mi][2][r] * a1;
      zh[mi][r] = y3 / (1.f + fexp2(-L2E * y3)) * (acc[mi][3][r] * a2);
      float g = fmaxf(fabsf(zl[mi][r]), fabsf(zh[mi][r]));
#pragma unroll
      for (int off = 1; off <= 8; off <<= 1) g = fmaxf(g, __shfl_xor(g, off));
      rm[mi][r] = g;  // this wave's 32-col max for the row
    }

  // cross-wave (wn pair: w and w^1 share wm) row-max via aliased staging LDS
  float* rmax = (float*)&As[0];  // [4][128] f32 = 2KB
  __syncthreads();               // all waves done reading staging
  if (lr == 0) {
#pragma unroll
    for (int mi = 0; mi < 8; ++mi)
#pragma unroll
      for (int r = 0; r < 4; ++r)
        rmax[w * 128 + mi * 16 + lg * 4 + r] = rm[mi][r];
  }
  __syncthreads();

#pragma unroll
  for (int mi = 0; mi < 8; ++mi)
#pragma unroll
    for (int r = 0; r < 4; ++r) {
      float g = fmaxf(rm[mi][r], rmax[(w ^ 1) * 128 + mi * 16 + lg * 4 + r]);
      float gmc = fmaxf(g, 1e-5f);
      float s = gmc * (1.f / 127.f);
      float inv = 127.f / gmc;
      int row = brow + wm * 128 + mi * 16 + lg * 4 + r;
      int zc = blockIdx.x * 64 + wn * 32 + lr;
      float q0 = fminf(fmaxf(rintf(zl[mi][r] * inv), -127.f), 127.f) * s;
      float q1 = fminf(fmaxf(rintf(zh[mi][r] * inv), -127.f), 127.f) * s;
      zq[(size_t)row * 4096 + zc] = f2bf(q0);
      zq[(size_t)row * 4096 + zc + 16] = f2bf(q1);
    }
}

// ---------------------------------------------------------------------------
// Causal flash attention + act_quant.  SWAPPED-OPERAND, block-staged.
// QBLK=128: 4 waves x 32 q-rows (2 Q B-frags per wave) -> K/V fragment
// reads (wave-invariant in q) amortize over 2x q-rows; barriers/q halve.
// KVBLK=64 double-buffered staging (global_load_lds, vmcnt(4) prefetch).
// Grid (16 heads, 32): qt = y<16?y:47-y -> every CU 2 blocks, 68 slots.
// ---------------------------------------------------------------------------
__global__ __launch_bounds__(256) void attn_kernel(
    const u16* __restrict__ QKV, const u16* __restrict__ Vt, u16* __restrict__ Y) {
  __shared__ u16 Ks[2][64 * 64];  // [k-token 64][d 64] swizzled, 16KB
  __shared__ u16 Vs[2][64 * 64];  // [d 64][k-token 64] swizzled, 16KB
  __shared__ u16 Ps[4][32 * 64];  // per-wave P^T [q 32][token 64], 16KB

  const int tid = threadIdx.x;
  const int l = tid & 63, w = tid >> 6;
  const int lr = l & 15, lg = l >> 4;
  const int xorv = (l & 7) << 4;
  const int h = blockIdx.x;
  const int y = blockIdx.y;
  const int qt = (y < 16) ? y : (47 - y);  // 128-row q-tile index, 0..31
  const int src_chunk = (l & 7) ^ (l >> 3);
  const int rl = w * 8 + (l >> 3);
  const float SC = 0.18033688f;            // 0.125 * log2(e)

  const int qrow0 = qt * 128 + w * 32;     // this wave's first q row
  const int nkt = 2 * qt + 2;

  // Q fragments: mi in {0,1} -> q rows qrow0 + mi*16 + lr
  bf16x8 qf[2][2];
#pragma unroll
  for (int mi = 0; mi < 2; ++mi)
#pragma unroll
    for (int ks = 0; ks < 2; ++ks)
      qf[mi][ks] = __builtin_bit_cast(
          bf16x8, *(const u16x8*)(QKV + (size_t)(qrow0 + mi * 16 + lr) * 3072 +
                                  h * 64 + ks * 32 + lg * 8));

  f32x4 O[2][4];  // O^T: lane holds O[q = qrow0+mi*16+lr][d = ni*16+lg*4+r]
#pragma unroll
  for (int mi = 0; mi < 2; ++mi)
#pragma unroll
    for (int ni = 0; ni < 4; ++ni) O[mi][ni] = (f32x4){0.f, 0.f, 0.f, 0.f};
  float m_[2] = {-3e38f, -3e38f}, lsum[2] = {0.f, 0.f};

  auto STAGE = [&](int buf, int kt) {
#pragma unroll
    for (int it = 0; it < 2; ++it) {
      int krow = kt * 64 + it * 32 + rl;  // token index (per-lane)
      gload16((const char*)QKV + ((size_t)krow * 3072 + 1024 + h * 64) * 2 + src_chunk * 16,
              &Ks[buf][(it * 32 + w * 8) * 64]);
      int drow = it * 32 + rl;            // head-dim index (per-lane)
      gload16((const char*)Vt + (((size_t)h * 64 + drow) * 4096 + kt * 64) * 2 + src_chunk * 16,
              &Vs[buf][(it * 32 + w * 8) * 64]);
    }
  };

  STAGE(0, 0);
#pragma unroll 1
  for (int kt = 0; kt < nkt; ++kt) {
    const int cur = kt & 1;
    if (kt + 1 < nkt) {
      STAGE(cur ^ 1, kt + 1);
      asm volatile("s_waitcnt vmcnt(4)" ::: "memory");  // current tile's 4 done
    } else {
      asm volatile("s_waitcnt vmcnt(0)" ::: "memory");
    }
    __builtin_amdgcn_s_barrier();
    __builtin_amdgcn_sched_barrier(0);

    const char* kbase = (const char*)&Ks[cur][0];
    const char* vbase = (const char*)&Vs[cur][0];

    // S^T[mi][ni] = mfma(K, Q[mi]) -- kf shared across mi
    f32x4 S[2][4];
    __builtin_amdgcn_s_setprio(1);
#pragma unroll
    for (int ni = 0; ni < 4; ++ni) {
      bf16x8 kf[2];
#pragma unroll
      for (int ks = 0; ks < 2; ++ks)
        kf[ks] = *(const bf16x8*)(kbase + (ni * 16 + lr) * 128 +
                                  ((ks * 64 + lg * 16) ^ xorv));
#pragma unroll
      for (int mi = 0; mi < 2; ++mi) {
        S[mi][ni] = (f32x4){0.f, 0.f, 0.f, 0.f};
#pragma unroll
        for (int ks = 0; ks < 2; ++ks)
          S[mi][ni] = __builtin_amdgcn_mfma_f32_16x16x32_bf16(kf[ks], qf[mi][ks],
                                                              S[mi][ni], 0, 0, 0);
      }
    }
    __builtin_amdgcn_s_setprio(0);

    // causal mask on raw S (wave-uniform condition)
    const int tb = kt * 64;
    if (tb + 63 > qrow0) {
#pragma unroll
      for (int mi = 0; mi < 2; ++mi)
#pragma unroll
        for (int ni = 0; ni < 4; ++ni)
#pragma unroll
          for (int r = 0; r < 4; ++r)
            if (tb + ni * 16 + lg * 4 + r > qrow0 + mi * 16 + lr) S[mi][ni][r] = -3e38f;
    }

    // online softmax per mi (lane owns its q-rows; row spans 4 lg-lanes)
#pragma unroll
    for (int mi = 0; mi < 2; ++mi) {
      float nm = -3e38f;
#pragma unroll
      for (int ni = 0; ni < 4; ++ni)
#pragma unroll
        for (int r = 0; r < 4; ++r) nm = fmaxf(nm, S[mi][ni][r]);
      nm = fmaxf(nm, __shfl_xor(nm, 16));
      nm = fmaxf(nm, __shfl_xor(nm, 32));
      float nms = nm * SC;
      if (__ballot(nms > m_[mi] + 8.f)) {  // T13 defer-rescale
        float mn = fmaxf(m_[mi], nms);
        float fac = fexp2(m_[mi] - mn);
        m_[mi] = mn;
        lsum[mi] *= fac;
#pragma unroll
        for (int ni = 0; ni < 4; ++ni) O[mi][ni] *= fac;
      }
      float rs = 0.f;
#pragma unroll
      for (int ni = 0; ni < 4; ++ni)
#pragma unroll
        for (int r = 0; r < 4; ++r) {
          float pv = fexp2(__builtin_fmaf(S[mi][ni][r], SC, -m_[mi]));
          S[mi][ni][r] = pv;
          rs += pv;
        }
      rs += __shfl_xor(rs, 16);
      rs += __shfl_xor(rs, 32);
      lsum[mi] += rs;
    }

    // P^T -> per-wave LDS via cvt_pk, rows mi*16+lr
#pragma unroll
    for (int mi = 0; mi < 2; ++mi)
#pragma unroll
      for (int ni = 0; ni < 4; ++ni) {
        u32x2 pk;
        pk[0] = cvtpk(S[mi][ni][0], S[mi][ni][1]);
        pk[1] = cvtpk(S[mi][ni][2], S[mi][ni][3]);
        *(u32x2*)((char*)&Ps[w][0] + (mi * 16 + lr) * 128 +
                  ((ni * 32 + lg * 8) ^ xorv)) = pk;
      }
    bf16x8 pt[2][2];
#pragma unroll
    for (int mi = 0; mi < 2; ++mi)
#pragma unroll
      for (int ks = 0; ks < 2; ++ks)
        pt[mi][ks] = *(const bf16x8*)((const char*)&Ps[w][0] + (mi * 16 + lr) * 128 +
                                      ((ks * 64 + lg * 16) ^ xorv));

    // O^T[mi][ni] += mfma(V^T, P^T[mi]) -- vf shared across mi
    __builtin_amdgcn_s_setprio(1);
#pragma unroll
    for (int ni = 0; ni < 4; ++ni) {
      bf16x8 vf[2];
#pragma unroll
      for (int ks = 0; ks < 2; ++ks)
        vf[ks] = *(const bf16x8*)(vbase + (ni * 16 + lr) * 128 +
                                  ((ks * 64 + lg * 16) ^ xorv));
#pragma unroll
      for (int mi = 0; mi < 2; ++mi)
#pragma unroll
        for (int ks = 0; ks < 2; ++ks)
          O[mi][ni] = __builtin_amdgcn_mfma_f32_16x16x32_bf16(vf[ks], pt[mi][ks],
                                                              O[mi][ni], 0, 0, 0);
    }
    __builtin_amdgcn_s_setprio(0);
    asm volatile("" ::: "memory");
    __builtin_amdgcn_s_barrier();
  }

  // epilogue: normalize + act_quant (group of 64 = this head's dims)
#pragma unroll
  for (int mi = 0; mi < 2; ++mi) {
    float rinv = 1.f / lsum[mi];
    float o[4][4];
    float gm = 0.f;
#pragma unroll
    for (int ni = 0; ni < 4; ++ni)
#pragma unroll
      for (int r = 0; r < 4; ++r) {
        o[ni][r] = O[mi][ni][r] * rinv;
        gm = fmaxf(gm, fabsf(o[ni][r]));
      }
    gm = fmaxf(gm, __shfl_xor(gm, 16));
    gm = fmaxf(gm, __shfl_xor(gm, 32));
    float gmc = fmaxf(gm, 1e-5f);
    float s = gmc * (1.f / 127.f);
    float inv = 127.f / gmc;
#pragma unroll
    for (int ni = 0; ni < 4; ++ni) {
      u16x4 ov;
#pragma unroll
      for (int r = 0; r < 4; ++r) {
        float q = fminf(fmaxf(rintf(o[ni][r] * inv), -127.f), 127.f) * s;
        ov[r] = f2bf(q);
      }
      *(u16x4*)(Y + (size_t)(qrow0 + mi * 16 + lr) * 1024 + h * 64 + ni * 16 + lg * 4) = ov;
    }
  }
}

// ---------------------------------------------------------------------------
extern "C" void kernel_launch(void* const* d_in, const int* in_sizes, int n_in,
                              void* d_out, int out_size, void* d_ws, size_t ws_size,
                              hipStream_t stream) {
  const float* x  = (const float*)d_in[0];
  const float* wq = (const float*)d_in[1];
  const float* wk = (const float*)d_in[2];
  const float* wv = (const float*)d_in[3];
  const float* wo = (const float*)d_in[4];
  const float* w1 = (const float*)d_in[5];
  const float* w2 = (const float*)d_in[6];
  const float* w3 = (const float*)d_in[7];
  const float* g1 = (const float*)d_in[8];
  const float* g2 = (const float*)d_in[9];

  char* ws = (char*)d_ws;
  const size_t MB = 1024 * 1024;
  u16* sgn   = (u16*)ws;
  u16* sWq   = (u16*)(ws + 0 * MB);
  u16* sWo   = (u16*)(ws + 6 * MB);
  u16* sW12  = (u16*)(ws + 8 * MB);    // fine-interleaved [8192,1024]
  u16* sW3   = (u16*)(ws + 24 * MB);
  float* partial = (float*)(ws + 32 * MB);
  float* alphas  = (float*)(ws + 32 * MB + 16384);
  u16* Vt    = (u16*)(ws + 33 * MB);   // dead before x1 written
  float* x1  = (float*)(ws + 33 * MB); // fp32 [4096,1024]
  u16* hq    = (u16*)(ws + 49 * MB);   // bf16 [4096,1024]
  u16* qkv   = (u16*)(ws + 57 * MB);   // bf16 [4096,3072]
  u16* yb    = (u16*)(ws + 81 * MB);   // bf16 [4096,1024]
  u16* zq    = (u16*)(ws + 57 * MB);   // bf16 [4096,4096] (qkv,yb dead)

  // weight prep + rmsnorm#1 (y==7) fused
  convert_sign_all<<<dim3(256, 8), 256, 0, stream>>>(wq, wk, wv, wo, w1, w2, w3,
                                                     sgn, partial, x, g1, hq);
  finalize_alpha<<<7, 256, 0, stream>>>(partial, alphas);

  // attention branch
  gemm_fat<false><<<dim3(24, 16), 256, 0, stream>>>(hq, sWq, alphas, 10, nullptr,
                                                    qkv, 4096, 3072, 1024);
  transpose_v<<<dim3(64, 16), 256, 0, stream>>>(qkv, Vt);
  attn_kernel<<<dim3(16, 32), 256, 0, stream>>>(qkv, Vt, yb);
  gemm_bt<true, 64><<<dim3(8, 64), 256, 0, stream>>>(yb, sWo, alphas + 3, 31, x,
                                                     x1, 4096, 1024, 1024);
  // FFN branch
  rmsnorm_quant<<<4096, 256, 0, stream>>>(x1, g2, hq);
  gemm_ffn<<<dim3(64, 16), 256, 0, stream>>>(hq, sW12, alphas + 4, zq);
  gemm_bt<true, 64><<<dim3(8, 64), 256, 0, stream>>>(zq, sW3, alphas + 6, 31, x1,
                                                     (float*)d_out, 4096, 1024, 4096);
}

// Round 15
// 300.642 us; speedup vs baseline: 1.4993x; 1.1077x over previous
//
#include <hip/hip_runtime.h>
#include <math.h>

// ============================================================================
// BitNet transformer block, MI355X (gfx950).  Round 15.
// R14 -> R15: attention = R11 skeleton (best measured, 93us) + TOKEN-SPLIT
// wave pairs. QBLK=64: waves 0-3 own 16 q-rows, tokens 0..31 of each 64-tok
// tile; waves 4-7 same q-rows, tokens 32..63; independent online-softmax
// states merged once at epilogue (O = a*O_lo + b*O_hi via dead staging LDS;
// all-masked hi states are annihilated exactly by b=exp2(-huge)=0).
// Per-wave tile work halves; grid (16,64)=1024 blocks x 8 waves -> 4
// blocks/CU, 32 waves/CU (LDS 40KB). qt = y<32?y:95-y -> 130 slots/CU const.
// Non-attn kernels unchanged (R11 state).
// ws layout (MB = 2^20): unchanged.
// ============================================================================

typedef unsigned short u16;
typedef unsigned int u32;
typedef __attribute__((ext_vector_type(2))) unsigned int u32x2;
typedef __attribute__((ext_vector_type(4))) float f32x4;
typedef __attribute__((ext_vector_type(4))) unsigned short u16x4;
typedef __attribute__((ext_vector_type(8))) unsigned short u16x8;
typedef __attribute__((ext_vector_type(8))) __bf16 bf16x8;

#define DEV static __device__ __forceinline__

DEV float bf2f(u16 u) { union { unsigned i; float f; } c; c.i = ((unsigned)u) << 16; return c.f; }
DEV u16 f2bf(float f) { __bf16 b = (__bf16)f; return __builtin_bit_cast(u16, b); }
DEV float fexp2(float x) { float r; asm("v_exp_f32 %0, %1" : "=v"(r) : "v"(x)); return r; }
DEV u32 cvtpk(float lo, float hi) {
  u32 r; asm("v_cvt_pk_bf16_f32 %0, %1, %2" : "=v"(r) : "v"(lo), "v"(hi)); return r;
}

DEV void gload16(const void* g, void* l) {
  __builtin_amdgcn_global_load_lds((__attribute__((address_space(1))) void*)g,
                                   (__attribute__((address_space(3))) void*)l,
                                   16, 0, 0);
}

// ---------------------------------------------------------------------------
// Weight prep: sign(w) -> bf16 {+1,-1,0}, block-partial |w| sums.
// wi 4/5 (w1/w2) interleave at 16-row granularity into one buffer at +8MB.
// wi==7: rmsnorm+act_quant of x (16 rows per block) - free overlap.
// ---------------------------------------------------------------------------
__global__ __launch_bounds__(256) void convert_sign_all(
    const float* __restrict__ w0, const float* __restrict__ w1,
    const float* __restrict__ w2, const float* __restrict__ w3,
    const float* __restrict__ w4, const float* __restrict__ w5,
    const float* __restrict__ w6, u16* __restrict__ sgn_base,
    float* __restrict__ partial,
    const float* __restrict__ x, const float* __restrict__ g1,
    u16* __restrict__ hq) {
  __shared__ float red[4];
  const int wi = blockIdx.y;
  const int t = threadIdx.x;

  if (wi == 7) {  // rmsnorm + act_quant for rows 16*bx .. +15
#pragma unroll 1
    for (int rr = 0; rr < 16; ++rr) {
      const int row = blockIdx.x * 16 + rr;
      f32x4 v = ((const f32x4*)(x + (size_t)row * 1024))[t];
      float ss = v[0] * v[0] + v[1] * v[1] + v[2] * v[2] + v[3] * v[3];
#pragma unroll
      for (int off = 32; off >= 1; off >>= 1) ss += __shfl_xor(ss, off);
      if ((t & 63) == 0) red[t >> 6] = ss;
      __syncthreads();
      float tot = red[0] + red[1] + red[2] + red[3];
      __syncthreads();
      float rinv = rsqrtf(tot * (1.f / 1024.f) + 1e-6f);
      f32x4 gg = ((const f32x4*)g1)[t];
      float n[4];
#pragma unroll
      for (int j = 0; j < 4; ++j) n[j] = v[j] * rinv * gg[j];
      float gm = fmaxf(fmaxf(fabsf(n[0]), fabsf(n[1])), fmaxf(fabsf(n[2]), fabsf(n[3])));
#pragma unroll
      for (int off = 1; off <= 8; off <<= 1) gm = fmaxf(gm, __shfl_xor(gm, off));
      float s = fmaxf(gm, 1e-5f) / 127.0f;
      u16x4 o;
#pragma unroll
      for (int j = 0; j < 4; ++j) {
        float q = fminf(fmaxf(rintf(n[j] / s), -127.f), 127.f) * s;
        o[j] = f2bf(q);
      }
      ((u16x4*)hq)[(size_t)row * 256 + t] = o;
    }
    return;
  }

  const float* srcs[7] = {w0, w1, w2, w3, w4, w5, w6};
  const size_t offs[7] = {0, 1048576, 2097152, 3145728, 4194304, 4194304, 12582912};
  const float* w = srcs[wi];
  u16* sgn = sgn_base + offs[wi];
  const int n4 = (wi < 4) ? 262144 : 1048576;
  const bool ilv = (wi == 4) || (wi == 5);
  const int ilv_add = (wi == 5) ? 16 : 0;

  float s = 0.f;
  for (int i = blockIdx.x * 256 + t; i < n4; i += 256 * 256) {
    f32x4 v = ((const f32x4*)w)[i];
    u16x4 o;
#pragma unroll
    for (int j = 0; j < 4; ++j) {
      float f = v[j];
      o[j] = f > 0.f ? (u16)0x3F80 : (f < 0.f ? (u16)0xBF80 : (u16)0);
      s += fabsf(f);
    }
    size_t di = i;
    if (ilv) {
      int e = i << 2;                 // element index
      int row = e >> 10, col = e & 1023;
      int dst = ((row >> 4) << 5) + ilv_add + (row & 15);
      di = ((size_t)dst << 8) + (col >> 2);
    }
    ((u16x4*)sgn)[di] = o;
  }
#pragma unroll
  for (int off = 32; off >= 1; off >>= 1) s += __shfl_xor(s, off);
  if ((t & 63) == 0) red[t >> 6] = s;
  __syncthreads();
  if (t == 0)
    partial[wi * 256 + blockIdx.x] = red[0] + red[1] + red[2] + red[3];
}

__global__ __launch_bounds__(256) void finalize_alpha(
    const float* __restrict__ partial, float* __restrict__ alphas) {
  __shared__ float red[4];
  int wi = blockIdx.x;  // 0..6
  float v = partial[wi * 256 + threadIdx.x];
#pragma unroll
  for (int off = 32; off >= 1; off >>= 1) v += __shfl_xor(v, off);
  if ((threadIdx.x & 63) == 0) red[threadIdx.x >> 6] = v;
  __syncthreads();
  if (threadIdx.x == 0)
    alphas[wi] = (red[0] + red[1] + red[2] + red[3]) *
                 (wi < 4 ? (1.f / 1048576.f) : (1.f / 4194304.f));
}

// ---------------------------------------------------------------------------
// RMSNorm + act_quant (group 64). One block per row of 1024.  (FFN branch)
// ---------------------------------------------------------------------------
__global__ __launch_bounds__(256) void rmsnorm_quant(
    const float* __restrict__ x, const float* __restrict__ g, u16* __restrict__ out) {
  __shared__ float red[4];
  const int row = blockIdx.x, t = threadIdx.x;
  f32x4 v = ((const f32x4*)(x + (size_t)row * 1024))[t];
  float ss = v[0] * v[0] + v[1] * v[1] + v[2] * v[2] + v[3] * v[3];
#pragma unroll
  for (int off = 32; off >= 1; off >>= 1) ss += __shfl_xor(ss, off);
  if ((t & 63) == 0) red[t >> 6] = ss;
  __syncthreads();
  float tot = red[0] + red[1] + red[2] + red[3];
  float rinv = rsqrtf(tot * (1.f / 1024.f) + 1e-6f);
  f32x4 gg = ((const f32x4*)g)[t];
  float n[4];
#pragma unroll
  for (int j = 0; j < 4; ++j) n[j] = v[j] * rinv * gg[j];
  float gm = fmaxf(fmaxf(fabsf(n[0]), fabsf(n[1])), fmaxf(fabsf(n[2]), fabsf(n[3])));
#pragma unroll
  for (int off = 1; off <= 8; off <<= 1) gm = fmaxf(gm, __shfl_xor(gm, off));
  float s = fmaxf(gm, 1e-5f) / 127.0f;
  u16x4 o;
#pragma unroll
  for (int j = 0; j < 4; ++j) {
    float q = fminf(fmaxf(rintf(n[j] / s), -127.f), 127.f) * s;
    o[j] = f2bf(q);
  }
  ((u16x4*)out)[(size_t)row * 256 + t] = o;
}

// ---------------------------------------------------------------------------
// V transpose: qkv[:,2048+h*64 .. +63] -> Vt[h][d][t]  ([16][64][4096] bf16).
// ---------------------------------------------------------------------------
__global__ __launch_bounds__(256) void transpose_v(
    const u16* __restrict__ qkv, u16* __restrict__ Vt) {
  __shared__ u16 T[64][65];
  const int tt = blockIdx.x, h = blockIdx.y, tid = threadIdx.x;
#pragma unroll
  for (int i = 0; i < 2; ++i) {
    int idx = i * 2048 + tid * 8;
    int trow = idx >> 6, dcol = idx & 63;
    u16x8 v = *(const u16x8*)(qkv + (size_t)(tt * 64 + trow) * 3072 + 2048 + h * 64 + dcol);
#pragma unroll
    for (int j = 0; j < 8; ++j) T[dcol + j][trow] = v[j];
  }
  __syncthreads();
#pragma unroll
  for (int i = 0; i < 2; ++i) {
    int idx = i * 2048 + tid * 8;
    int drow = idx >> 6, tcol = idx & 63;
    u16x8 v;
#pragma unroll
    for (int j = 0; j < 8; ++j) v[j] = T[drow][tcol + j];
    *(u16x8*)(Vt + ((size_t)h * 64 + drow) * 4096 + tt * 64 + tcol) = v;
  }
}

// ---------------------------------------------------------------------------
// GEMM: C[M,N] = alpha[bcol>>ashift] * (A[M,K] @ B[N,K]^T) (+res).
// BMx128 tile, BK=64, 4 waves, global_load_lds w=16, XOR swizzle.
// ---------------------------------------------------------------------------
template <bool RES, int BM>
__global__ __launch_bounds__(256) void gemm_bt(
    const u16* __restrict__ A, const u16* __restrict__ B,
    const float* __restrict__ alpha, int ashift, const float* __restrict__ res,
    void* __restrict__ Cout, int M, int N, int K) {
  constexpr int NI = (BM == 128) ? 4 : 2;
  constexpr int WNE = (BM == 128) ? 64 : 32;
  __shared__ u16 As[BM * 64];
  __shared__ u16 Bs[128 * 64];
  const int tid = threadIdx.x;
  const int l = tid & 63, w = tid >> 6;
  const int wm = (BM == 128) ? (w >> 1) : 0;
  const int wn = (BM == 128) ? (w & 1) : w;
  const int lr = l & 15, lg = l >> 4;
  const int xorv = (l & 7) << 4;
  const int brow = blockIdx.y * BM;
  const int bcol = blockIdx.x * 128;
  const int src_chunk = (l & 7) ^ (l >> 3);
  const int rl = w * 8 + (l >> 3);

  f32x4 acc[4][NI];
#pragma unroll
  for (int i = 0; i < 4; ++i)
#pragma unroll
    for (int j = 0; j < NI; ++j) acc[i][j] = (f32x4){0.f, 0.f, 0.f, 0.f};

  const char* Ag = (const char*)A;
  const char* Bg = (const char*)B;
  const int nkt = K >> 6;
  for (int kt = 0; kt < nkt; ++kt) {
    __syncthreads();
    const size_t kb = (size_t)kt * 128 + src_chunk * 16;
#pragma unroll
    for (int it = 0; it < BM / 32; ++it)
      gload16(Ag + (size_t)(brow + it * 32 + rl) * (size_t)(K * 2) + kb,
              &As[(it * 32 + w * 8) * 64]);
#pragma unroll
    for (int it = 0; it < 4; ++it)
      gload16(Bg + (size_t)(bcol + it * 32 + rl) * (size_t)(K * 2) + kb,
              &Bs[(it * 32 + w * 8) * 64]);
    __syncthreads();

    bf16x8 af[4][2], bfr[NI][2];
#pragma unroll
    for (int mi = 0; mi < 4; ++mi)
#pragma unroll
      for (int ks = 0; ks < 2; ++ks) {
        int row = wm * 64 + mi * 16 + lr;
        af[mi][ks] = *(const bf16x8*)((const char*)As + row * 128 + ((ks * 64 + lg * 16) ^ xorv));
      }
#pragma unroll
    for (int ni = 0; ni < NI; ++ni)
#pragma unroll
      for (int ks = 0; ks < 2; ++ks) {
        int row = wn * WNE + ni * 16 + lr;
        bfr[ni][ks] = *(const bf16x8*)((const char*)Bs + row * 128 + ((ks * 64 + lg * 16) ^ xorv));
      }
#pragma unroll
    for (int ks = 0; ks < 2; ++ks)
#pragma unroll
      for (int mi = 0; mi < 4; ++mi)
#pragma unroll
        for (int ni = 0; ni < NI; ++ni)
          acc[mi][ni] = __builtin_amdgcn_mfma_f32_16x16x32_bf16(
              af[mi][ks], bfr[ni][ks], acc[mi][ni], 0, 0, 0);
  }

  const float scale = alpha[bcol >> ashift];
#pragma unroll
  for (int mi = 0; mi < 4; ++mi)
#pragma unroll
    for (int ni = 0; ni < NI; ++ni)
#pragma unroll
      for (int r = 0; r < 4; ++r) {
        int row = brow + wm * 64 + mi * 16 + lg * 4 + r;
        int col = bcol + wn * WNE + ni * 16 + lr;
        float vv = acc[mi][ni][r] * scale;
        if (RES)
          ((float*)Cout)[(size_t)row * N + col] = res[(size_t)row * N + col] + vv;
        else
          ((u16*)Cout)[(size_t)row * N + col] = f2bf(vv);
      }
}

// ---------------------------------------------------------------------------
// Fat-wave GEMM: 256(M) x 128(N) tile, 4 waves, per-wave 128x64 output.
// 24 LDS reads / 64 MFMA per wave-iter. Used for the QKV projection.
// ---------------------------------------------------------------------------
template <bool RES>
__global__ __launch_bounds__(256, 2) void gemm_fat(
    const u16* __restrict__ A, const u16* __restrict__ B,
    const float* __restrict__ alpha, int ashift, const float* __restrict__ res,
    void* __restrict__ Cout, int M, int N, int K) {
  __shared__ u16 As[256 * 64];  // 32KB
  __shared__ u16 Bs[128 * 64];  // 16KB
  const int tid = threadIdx.x;
  const int l = tid & 63, w = tid >> 6;
  const int wm = w >> 1, wn = w & 1;
  const int lr = l & 15, lg = l >> 4;
  const int xorv = (l & 7) << 4;
  const int brow = blockIdx.y * 256;
  const int bcol = blockIdx.x * 128;
  const int src_chunk = (l & 7) ^ (l >> 3);
  const int rl = w * 8 + (l >> 3);

  f32x4 acc[8][4];
#pragma unroll
  for (int i = 0; i < 8; ++i)
#pragma unroll
    for (int j = 0; j < 4; ++j) acc[i][j] = (f32x4){0.f, 0.f, 0.f, 0.f};

  const int nkt = K >> 6;
  for (int kt = 0; kt < nkt; ++kt) {
    __syncthreads();
    const size_t kb = (size_t)kt * 128 + src_chunk * 16;
#pragma unroll
    for (int it = 0; it < 8; ++it)
      gload16((const char*)A + (size_t)(brow + it * 32 + rl) * (size_t)(K * 2) + kb,
              &As[(it * 32 + w * 8) * 64]);
#pragma unroll
    for (int it = 0; it < 4; ++it)
      gload16((const char*)B + (size_t)(bcol + it * 32 + rl) * (size_t)(K * 2) + kb,
              &Bs[(it * 32 + w * 8) * 64]);
    __syncthreads();

#pragma unroll
    for (int ks = 0; ks < 2; ++ks) {
      bf16x8 bfr[4];
#pragma unroll
      for (int ni = 0; ni < 4; ++ni)
        bfr[ni] = *(const bf16x8*)((const char*)Bs + (wn * 64 + ni * 16 + lr) * 128 +
                                   ((ks * 64 + lg * 16) ^ xorv));
#pragma unroll
      for (int mi = 0; mi < 8; ++mi) {
        bf16x8 af = *(const bf16x8*)((const char*)As + (wm * 128 + mi * 16 + lr) * 128 +
                                     ((ks * 64 + lg * 16) ^ xorv));
#pragma unroll
        for (int ni = 0; ni < 4; ++ni)
          acc[mi][ni] = __builtin_amdgcn_mfma_f32_16x16x32_bf16(
              af, bfr[ni], acc[mi][ni], 0, 0, 0);
      }
    }
  }

  const float scale = alpha[bcol >> ashift];
#pragma unroll
  for (int mi = 0; mi < 8; ++mi)
#pragma unroll
    for (int ni = 0; ni < 4; ++ni)
#pragma unroll
      for (int r = 0; r < 4; ++r) {
        int row = brow + wm * 128 + mi * 16 + lg * 4 + r;
        int col = bcol + wn * 64 + ni * 16 + lr;
        float vv = acc[mi][ni][r] * scale;
        if (RES)
          ((float*)Cout)[(size_t)row * N + col] = res[(size_t)row * N + col] + vv;
        else
          ((u16*)Cout)[(size_t)row * N + col] = f2bf(vv);
      }
}

// ---------------------------------------------------------------------------
// Fused FFN GEMM, fat-wave: tile 256(M) x 128(W12 rows = 64 z-cols),
// 4 waves, per-wave output 128x64 (acc 8x4). W12 fine-interleaved (16-row).
// ---------------------------------------------------------------------------
__global__ __launch_bounds__(256, 2) void gemm_ffn(
    const u16* __restrict__ A, const u16* __restrict__ B12,
    const float* __restrict__ alpha2, u16* __restrict__ zq) {
  __shared__ u16 As[256 * 64];  // 32KB
  __shared__ u16 Bs[128 * 64];  // 16KB
  const int tid = threadIdx.x;
  const int l = tid & 63, w = tid >> 6;
  const int wm = w >> 1, wn = w & 1;
  const int lr = l & 15, lg = l >> 4;
  const int xorv = (l & 7) << 4;
  const int brow = blockIdx.y * 256;
  const int bcol = blockIdx.x * 128;  // W12 row block = 64 z-cols
  const int src_chunk = (l & 7) ^ (l >> 3);
  const int rl = w * 8 + (l >> 3);

  f32x4 acc[8][4];
#pragma unroll
  for (int i = 0; i < 8; ++i)
#pragma unroll
    for (int j = 0; j < 4; ++j) acc[i][j] = (f32x4){0.f, 0.f, 0.f, 0.f};

  for (int kt = 0; kt < 16; ++kt) {
    __syncthreads();
    const size_t kb = (size_t)kt * 128 + src_chunk * 16;
#pragma unroll
    for (int it = 0; it < 8; ++it)
      gload16((const char*)A + (size_t)(brow + it * 32 + rl) * 2048 + kb,
              &As[(it * 32 + w * 8) * 64]);
#pragma unroll
    for (int it = 0; it < 4; ++it)
      gload16((const char*)B12 + (size_t)(bcol + it * 32 + rl) * 2048 + kb,
              &Bs[(it * 32 + w * 8) * 64]);
    __syncthreads();

#pragma unroll
    for (int ks = 0; ks < 2; ++ks) {
      bf16x8 bfr[4];
#pragma unroll
      for (int ni = 0; ni < 4; ++ni)
        bfr[ni] = *(const bf16x8*)((const char*)Bs + (wn * 64 + ni * 16 + lr) * 128 +
                                   ((ks * 64 + lg * 16) ^ xorv));
#pragma unroll
      for (int mi = 0; mi < 8; ++mi) {
        bf16x8 af = *(const bf16x8*)((const char*)As + (wm * 128 + mi * 16 + lr) * 128 +
                                     ((ks * 64 + lg * 16) ^ xorv));
#pragma unroll
        for (int ni = 0; ni < 4; ++ni)
          acc[mi][ni] = __builtin_amdgcn_mfma_f32_16x16x32_bf16(
              af, bfr[ni], acc[mi][ni], 0, 0, 0);
      }
    }
  }

  // ---- epilogue: z = silu(a1*y1)*(a2*y2) in-register ----
  const float a1 = alpha2[0], a2 = alpha2[1];
  const float L2E = 1.4426950408889634f;
  float zl[8][4], zh[8][4], rm[8][4];
#pragma unroll
  for (int mi = 0; mi < 8; ++mi)
#pragma unroll
    for (int r = 0; r < 4; ++r) {
      float y1 = acc[mi][0][r] * a1;
      zl[mi][r] = y1 / (1.f + fexp2(-L2E * y1)) * (acc[mi][1][r] * a2);
      float y3 = acc[mi][2][r] * a1;
      zh[mi][r] = y3 / (1.f + fexp2(-L2E * y3)) * (acc[mi][3][r] * a2);
      float g = fmaxf(fabsf(zl[mi][r]), fabsf(zh[mi][r]));
#pragma unroll
      for (int off = 1; off <= 8; off <<= 1) g = fmaxf(g, __shfl_xor(g, off));
      rm[mi][r] = g;  // this wave's 32-col max for the row
    }

  // cross-wave (wn pair: w and w^1 share wm) row-max via aliased staging LDS
  float* rmax = (float*)&As[0];  // [4][128] f32 = 2KB
  __syncthreads();               // all waves done reading staging
  if (lr == 0) {
#pragma unroll
    for (int mi = 0; mi < 8; ++mi)
#pragma unroll
      for (int r = 0; r < 4; ++r)
        rmax[w * 128 + mi * 16 + lg * 4 + r] = rm[mi][r];
  }
  __syncthreads();

#pragma unroll
  for (int mi = 0; mi < 8; ++mi)
#pragma unroll
    for (int r = 0; r < 4; ++r) {
      float g = fmaxf(rm[mi][r], rmax[(w ^ 1) * 128 + mi * 16 + lg * 4 + r]);
      float gmc = fmaxf(g, 1e-5f);
      float s = gmc * (1.f / 127.f);
      float inv = 127.f / gmc;
      int row = brow + wm * 128 + mi * 16 + lg * 4 + r;
      int zc = blockIdx.x * 64 + wn * 32 + lr;
      float q0 = fminf(fmaxf(rintf(zl[mi][r] * inv), -127.f), 127.f) * s;
      float q1 = fminf(fmaxf(rintf(zh[mi][r] * inv), -127.f), 127.f) * s;
      zq[(size_t)row * 4096 + zc] = f2bf(q0);
      zq[(size_t)row * 4096 + zc + 16] = f2bf(q1);
    }
}

// ---------------------------------------------------------------------------
// Causal flash attention + act_quant.  SWAPPED-OPERAND, TOKEN-SPLIT pairs.
// QBLK=64, 8 waves: wave w -> q-group wq=w&3 (16 rows), token half tw=w>>2
// (32 of each 64-token tile). Independent online softmax per wave; merged at
// epilogue via dead staging LDS. KVBLK=64 dbuf staging (R11 pattern).
// Grid (16 heads, 64): qt = y<32?y:95-y -> 4 blocks/CU, 130 slots, 32 w/CU.
// ---------------------------------------------------------------------------
__global__ __launch_bounds__(512) void attn_kernel(
    const u16* __restrict__ QKV, const u16* __restrict__ Vt, u16* __restrict__ Y) {
  __shared__ u16 Ks[2][64 * 64];  // [k-token 64][d 64] swizzled, 16KB
  __shared__ u16 Vs[2][64 * 64];  // [d 64][k-token 64] swizzled, 16KB
  __shared__ u16 Ps[8][16 * 32];  // per-wave P^T [16 q][32 tok], 8KB

  const int tid = threadIdx.x;
  const int l = tid & 63, w = tid >> 6;  // 8 waves
  const int wq = w & 3, tw = w >> 2;     // q-group, token half
  const int lr = l & 15, lg = l >> 4;
  const int xorv = (l & 7) << 4;
  const int psw = (l & 3) << 4;          // P-row swizzle (64B rows)
  const int h = blockIdx.x;
  const int y = blockIdx.y;
  const int qt = (y < 32) ? y : (95 - y);  // 64-row q-tile index
  const int rl = w * 8 + (l >> 3);         // staging row 0..63
  const float SC = 0.18033688f;            // 0.125 * log2(e)

  const int qrow0 = qt * 64 + wq * 16;     // this wave's first q row
  const int nkt = qt + 1;

  bf16x8 qf[2];
#pragma unroll
  for (int ks = 0; ks < 2; ++ks)
    qf[ks] = __builtin_bit_cast(
        bf16x8, *(const u16x8*)(QKV + (size_t)(qrow0 + lr) * 3072 +
                                h * 64 + ks * 32 + lg * 8));

  f32x4 O[4];  // O^T: lane holds O[q=qrow0+lr][d = ni*16 + lg*4 + r] (partial)
#pragma unroll
  for (int ni = 0; ni < 4; ++ni) O[ni] = (f32x4){0.f, 0.f, 0.f, 0.f};
  float m_ = -3e38f, lsum = 0.f;

  auto STAGE = [&](int buf, int kt) {
    int krow = kt * 64 + rl;
    gload16((const char*)QKV + ((size_t)krow * 3072 + 1024 + h * 64) * 2 +
                ((l & 7) ^ (l >> 3)) * 16,
            &Ks[buf][(w * 8) * 64]);
    gload16((const char*)Vt + (((size_t)h * 64 + rl) * 4096 + kt * 64) * 2 +
                ((l & 7) ^ (l >> 3)) * 16,
            &Vs[buf][(w * 8) * 64]);
  };

  STAGE(0, 0);
#pragma unroll 1
  for (int kt = 0; kt < nkt; ++kt) {
    const int cur = kt & 1;
    if (kt + 1 < nkt) {
      STAGE(cur ^ 1, kt + 1);
      asm volatile("s_waitcnt vmcnt(2)" ::: "memory");  // current tile's 2 done
    } else {
      asm volatile("s_waitcnt vmcnt(0)" ::: "memory");
    }
    __builtin_amdgcn_s_barrier();
    __builtin_amdgcn_sched_barrier(0);

    const char* kbase = (const char*)&Ks[cur][0];
    const char* vbase = (const char*)&Vs[cur][0];

    // S^T[ni] = mfma(K, Q): tokens tw*32 + ni*16 + lr (ni in {0,1})
    f32x4 S[2];
    __builtin_amdgcn_s_setprio(1);
#pragma unroll
    for (int ni = 0; ni < 2; ++ni) {
      S[ni] = (f32x4){0.f, 0.f, 0.f, 0.f};
#pragma unroll
      for (int ks = 0; ks < 2; ++ks) {
        bf16x8 kf = *(const bf16x8*)(kbase + (tw * 32 + ni * 16 + lr) * 128 +
                                     ((ks * 64 + lg * 16) ^ xorv));
        S[ni] = __builtin_amdgcn_mfma_f32_16x16x32_bf16(kf, qf[ks], S[ni], 0, 0, 0);
      }
    }
    __builtin_amdgcn_s_setprio(0);

    // V fragments (all 4 d-tiles, this wave's 32 tokens)
    bf16x8 vf[4];
#pragma unroll
    for (int ni = 0; ni < 4; ++ni)
      vf[ni] = *(const bf16x8*)(vbase + (ni * 16 + lr) * 128 +
                                ((tw * 64 + lg * 16) ^ xorv));

    // causal mask on raw S
    const int tb = kt * 64 + tw * 32;
    if (tb + 31 > qrow0) {
#pragma unroll
      for (int ni = 0; ni < 2; ++ni)
#pragma unroll
        for (int r = 0; r < 4; ++r)
          if (tb + ni * 16 + lg * 4 + r > qrow0 + lr) S[ni][r] = -3e38f;
    }

    // online softmax over this wave's 32 tokens (row spans 4 lg-lanes)
    float nm = fmaxf(fmaxf(S[0][0], S[0][1]), fmaxf(S[0][2], S[0][3]));
    nm = fmaxf(nm, fmaxf(fmaxf(S[1][0], S[1][1]), fmaxf(S[1][2], S[1][3])));
    nm = fmaxf(nm, __shfl_xor(nm, 16));
    nm = fmaxf(nm, __shfl_xor(nm, 32));
    float nms = nm * SC;
    if (__ballot(nms > m_ + 8.f)) {  // T13 defer-rescale
      float mn = fmaxf(m_, nms);
      float fac = fexp2(m_ - mn);
      m_ = mn;
      lsum *= fac;
#pragma unroll
      for (int ni = 0; ni < 4; ++ni) O[ni] *= fac;
    }
    float rs = 0.f;
#pragma unroll
    for (int ni = 0; ni < 2; ++ni)
#pragma unroll
      for (int r = 0; r < 4; ++r) {
        float pv = fexp2(__builtin_fmaf(S[ni][r], SC, -m_));
        S[ni][r] = pv;
        rs += pv;
      }
    rs += __shfl_xor(rs, 16);
    rs += __shfl_xor(rs, 32);
    lsum += rs;

    // P^T -> wave-private LDS [16 q][32 tok] (64B rows, swizzled)
#pragma unroll
    for (int ni = 0; ni < 2; ++ni) {
      u32x2 pk;
      pk[0] = cvtpk(S[ni][0], S[ni][1]);
      pk[1] = cvtpk(S[ni][2], S[ni][3]);
      *(u32x2*)((char*)&Ps[w][0] + lr * 64 + ((ni * 32 + lg * 8) ^ psw)) = pk;
    }
    bf16x8 pt = *(const bf16x8*)((const char*)&Ps[w][0] + lr * 64 +
                                 ((lg * 16) ^ psw));

    // O^T[ni] += mfma(V^T, P^T)  (K=32: one mfma per d-tile)
    __builtin_amdgcn_s_setprio(1);
#pragma unroll
    for (int ni = 0; ni < 4; ++ni)
      O[ni] = __builtin_amdgcn_mfma_f32_16x16x32_bf16(vf[ni], pt, O[ni], 0, 0, 0);
    __builtin_amdgcn_s_setprio(0);
    asm volatile("" ::: "memory");
    __builtin_amdgcn_s_barrier();  // protect buf before next STAGE overwrites
  }

  // ---- epilogue: merge token halves, normalize, act_quant ----
  __syncthreads();  // all waves done with staging buffers
  float* exO = (float*)&Vs[0][0];  // [4 pair][64 lane][16] f32 = 16KB
  float* exM = (float*)&Ks[0][0];  // [4 pair][64 lane][2] f32 = 2KB
  if (tw == 1) {
#pragma unroll
    for (int ni = 0; ni < 4; ++ni)
      *(f32x4*)&exO[(size_t)wq * 1024 + l * 16 + ni * 4] = O[ni];
    exM[wq * 128 + l * 2] = m_;
    exM[wq * 128 + l * 2 + 1] = lsum;
  }
  __syncthreads();
  if (tw == 0) {
    float mh = exM[wq * 128 + l * 2];
    float lh = exM[wq * 128 + l * 2 + 1];
    float M = fmaxf(m_, mh);
    float a = fexp2(m_ - M);
    float b = fexp2(mh - M);
    float ls = a * lsum + b * lh;
    float rinv = 1.f / ls;
    float o[4][4];
    float gm = 0.f;
#pragma unroll
    for (int ni = 0; ni < 4; ++ni) {
      f32x4 Oh = *(const f32x4*)&exO[(size_t)wq * 1024 + l * 16 + ni * 4];
#pragma unroll
      for (int r = 0; r < 4; ++r) {
        o[ni][r] = (a * O[ni][r] + b * Oh[r]) * rinv;
        gm = fmaxf(gm, fabsf(o[ni][r]));
      }
    }
    gm = fmaxf(gm, __shfl_xor(gm, 16));
    gm = fmaxf(gm, __shfl_xor(gm, 32));
    float gmc = fmaxf(gm, 1e-5f);
    float s = gmc * (1.f / 127.f);
    float inv = 127.f / gmc;
#pragma unroll
    for (int ni = 0; ni < 4; ++ni) {
      u16x4 ov;
#pragma unroll
      for (int r = 0; r < 4; ++r) {
        float q = fminf(fmaxf(rintf(o[ni][r] * inv), -127.f), 127.f) * s;
        ov[r] = f2bf(q);
      }
      *(u16x4*)(Y + (size_t)(qrow0 + lr) * 1024 + h * 64 + ni * 16 + lg * 4) = ov;
    }
  }
}

// ---------------------------------------------------------------------------
extern "C" void kernel_launch(void* const* d_in, const int* in_sizes, int n_in,
                              void* d_out, int out_size, void* d_ws, size_t ws_size,
                              hipStream_t stream) {
  const float* x  = (const float*)d_in[0];
  const float* wq = (const float*)d_in[1];
  const float* wk = (const float*)d_in[2];
  const float* wv = (const float*)d_in[3];
  const float* wo = (const float*)d_in[4];
  const float* w1 = (const float*)d_in[5];
  const float* w2 = (const float*)d_in[6];
  const float* w3 = (const float*)d_in[7];
  const float* g1 = (const float*)d_in[8];
  const float* g2 = (const float*)d_in[9];

  char* ws = (char*)d_ws;
  const size_t MB = 1024 * 1024;
  u16* sgn   = (u16*)ws;
  u16* sWq   = (u16*)(ws + 0 * MB);
  u16* sWo   = (u16*)(ws + 6 * MB);
  u16* sW12  = (u16*)(ws + 8 * MB);    // fine-interleaved [8192,1024]
  u16* sW3   = (u16*)(ws + 24 * MB);
  float* partial = (float*)(ws + 32 * MB);
  float* alphas  = (float*)(ws + 32 * MB + 16384);
  u16* Vt    = (u16*)(ws + 33 * MB);   // dead before x1 written
  float* x1  = (float*)(ws + 33 * MB); // fp32 [4096,1024]
  u16* hq    = (u16*)(ws + 49 * MB);   // bf16 [4096,1024]
  u16* qkv   = (u16*)(ws + 57 * MB);   // bf16 [4096,3072]
  u16* yb    = (u16*)(ws + 81 * MB);   // bf16 [4096,1024]
  u16* zq    = (u16*)(ws + 57 * MB);   // bf16 [4096,4096] (qkv,yb dead)

  // weight prep + rmsnorm#1 (y==7) fused
  convert_sign_all<<<dim3(256, 8), 256, 0, stream>>>(wq, wk, wv, wo, w1, w2, w3,
                                                     sgn, partial, x, g1, hq);
  finalize_alpha<<<7, 256, 0, stream>>>(partial, alphas);

  // attention branch
  gemm_fat<false><<<dim3(24, 16), 256, 0, stream>>>(hq, sWq, alphas, 10, nullptr,
                                                    qkv, 4096, 3072, 1024);
  transpose_v<<<dim3(64, 16), 256, 0, stream>>>(qkv, Vt);
  attn_kernel<<<dim3(16, 64), 512, 0, stream>>>(qkv, Vt, yb);
  gemm_bt<true, 64><<<dim3(8, 64), 256, 0, stream>>>(yb, sWo, alphas + 3, 31, x,
                                                     x1, 4096, 1024, 1024);
  // FFN branch
  rmsnorm_quant<<<4096, 256, 0, stream>>>(x1, g2, hq);
  gemm_ffn<<<dim3(64, 16), 256, 0, stream>>>(hq, sW12, alphas + 4, zq);
  gemm_bt<true, 64><<<dim3(8, 64), 256, 0, stream>>>(zq, sW3, alphas + 6, 31, x1,
                                                     (float*)d_out, 4096, 1024, 4096);
}

// Round 17
// 297.243 us; speedup vs baseline: 1.5165x; 1.0114x over previous
//
#include <hip/hip_runtime.h>
#include <math.h>

// ============================================================================
// BitNet transformer block, MI355X (gfx950).  Round 17.
// R16 (register-P) produced NaN -> reverted to R15 (passing, 300.6us).
// R17 = R15 + conflict-free P buffer: R15's 64B P-rows were 4-way bank
// conflicted (8e6 conflicts, lanes lr,lr+4,lr+8,lr+12 alias). Widen to the
// R11-proven layout: Ps[8][16*64] (128B rows), write u32x2 at
// lr*128+((ni*32+lg*8)^xorv), read b128 at lr*128+((lg*16)^xorv) ->
// 2-way aliasing only (free). V natural order (transpose_v = R15).
// LDS 48KB. Everything else identical to the passing R15 kernel.
// ws layout (MB = 2^20): unchanged.
// ============================================================================

typedef unsigned short u16;
typedef unsigned int u32;
typedef __attribute__((ext_vector_type(2))) unsigned int u32x2;
typedef __attribute__((ext_vector_type(4))) float f32x4;
typedef __attribute__((ext_vector_type(4))) unsigned short u16x4;
typedef __attribute__((ext_vector_type(8))) unsigned short u16x8;
typedef __attribute__((ext_vector_type(8))) __bf16 bf16x8;

#define DEV static __device__ __forceinline__

DEV float bf2f(u16 u) { union { unsigned i; float f; } c; c.i = ((unsigned)u) << 16; return c.f; }
DEV u16 f2bf(float f) { __bf16 b = (__bf16)f; return __builtin_bit_cast(u16, b); }
DEV float fexp2(float x) { float r; asm("v_exp_f32 %0, %1" : "=v"(r) : "v"(x)); return r; }
DEV u32 cvtpk(float lo, float hi) {
  u32 r; asm("v_cvt_pk_bf16_f32 %0, %1, %2" : "=v"(r) : "v"(lo), "v"(hi)); return r;
}

DEV void gload16(const void* g, void* l) {
  __builtin_amdgcn_global_load_lds((__attribute__((address_space(1))) void*)g,
                                   (__attribute__((address_space(3))) void*)l,
                                   16, 0, 0);
}

// ---------------------------------------------------------------------------
// Weight prep: sign(w) -> bf16 {+1,-1,0}, block-partial |w| sums.
// wi 4/5 (w1/w2) interleave at 16-row granularity into one buffer at +8MB.
// wi==7: rmsnorm+act_quant of x (16 rows per block) - free overlap.
// ---------------------------------------------------------------------------
__global__ __launch_bounds__(256) void convert_sign_all(
    const float* __restrict__ w0, const float* __restrict__ w1,
    const float* __restrict__ w2, const float* __restrict__ w3,
    const float* __restrict__ w4, const float* __restrict__ w5,
    const float* __restrict__ w6, u16* __restrict__ sgn_base,
    float* __restrict__ partial,
    const float* __restrict__ x, const float* __restrict__ g1,
    u16* __restrict__ hq) {
  __shared__ float red[4];
  const int wi = blockIdx.y;
  const int t = threadIdx.x;

  if (wi == 7) {  // rmsnorm + act_quant for rows 16*bx .. +15
#pragma unroll 1
    for (int rr = 0; rr < 16; ++rr) {
      const int row = blockIdx.x * 16 + rr;
      f32x4 v = ((const f32x4*)(x + (size_t)row * 1024))[t];
      float ss = v[0] * v[0] + v[1] * v[1] + v[2] * v[2] + v[3] * v[3];
#pragma unroll
      for (int off = 32; off >= 1; off >>= 1) ss += __shfl_xor(ss, off);
      if ((t & 63) == 0) red[t >> 6] = ss;
      __syncthreads();
      float tot = red[0] + red[1] + red[2] + red[3];
      __syncthreads();
      float rinv = rsqrtf(tot * (1.f / 1024.f) + 1e-6f);
      f32x4 gg = ((const f32x4*)g1)[t];
      float n[4];
#pragma unroll
      for (int j = 0; j < 4; ++j) n[j] = v[j] * rinv * gg[j];
      float gm = fmaxf(fmaxf(fabsf(n[0]), fabsf(n[1])), fmaxf(fabsf(n[2]), fabsf(n[3])));
#pragma unroll
      for (int off = 1; off <= 8; off <<= 1) gm = fmaxf(gm, __shfl_xor(gm, off));
      float s = fmaxf(gm, 1e-5f) / 127.0f;
      u16x4 o;
#pragma unroll
      for (int j = 0; j < 4; ++j) {
        float q = fminf(fmaxf(rintf(n[j] / s), -127.f), 127.f) * s;
        o[j] = f2bf(q);
      }
      ((u16x4*)hq)[(size_t)row * 256 + t] = o;
    }
    return;
  }

  const float* srcs[7] = {w0, w1, w2, w3, w4, w5, w6};
  const size_t offs[7] = {0, 1048576, 2097152, 3145728, 4194304, 4194304, 12582912};
  const float* w = srcs[wi];
  u16* sgn = sgn_base + offs[wi];
  const int n4 = (wi < 4) ? 262144 : 1048576;
  const bool ilv = (wi == 4) || (wi == 5);
  const int ilv_add = (wi == 5) ? 16 : 0;

  float s = 0.f;
  for (int i = blockIdx.x * 256 + t; i < n4; i += 256 * 256) {
    f32x4 v = ((const f32x4*)w)[i];
    u16x4 o;
#pragma unroll
    for (int j = 0; j < 4; ++j) {
      float f = v[j];
      o[j] = f > 0.f ? (u16)0x3F80 : (f < 0.f ? (u16)0xBF80 : (u16)0);
      s += fabsf(f);
    }
    size_t di = i;
    if (ilv) {
      int e = i << 2;                 // element index
      int row = e >> 10, col = e & 1023;
      int dst = ((row >> 4) << 5) + ilv_add + (row & 15);
      di = ((size_t)dst << 8) + (col >> 2);
    }
    ((u16x4*)sgn)[di] = o;
  }
#pragma unroll
  for (int off = 32; off >= 1; off >>= 1) s += __shfl_xor(s, off);
  if ((t & 63) == 0) red[t >> 6] = s;
  __syncthreads();
  if (t == 0)
    partial[wi * 256 + blockIdx.x] = red[0] + red[1] + red[2] + red[3];
}

__global__ __launch_bounds__(256) void finalize_alpha(
    const float* __restrict__ partial, float* __restrict__ alphas) {
  __shared__ float red[4];
  int wi = blockIdx.x;  // 0..6
  float v = partial[wi * 256 + threadIdx.x];
#pragma unroll
  for (int off = 32; off >= 1; off >>= 1) v += __shfl_xor(v, off);
  if ((threadIdx.x & 63) == 0) red[threadIdx.x >> 6] = v;
  __syncthreads();
  if (threadIdx.x == 0)
    alphas[wi] = (red[0] + red[1] + red[2] + red[3]) *
                 (wi < 4 ? (1.f / 1048576.f) : (1.f / 4194304.f));
}

// ---------------------------------------------------------------------------
// RMSNorm + act_quant (group 64). One block per row of 1024.  (FFN branch)
// ---------------------------------------------------------------------------
__global__ __launch_bounds__(256) void rmsnorm_quant(
    const float* __restrict__ x, const float* __restrict__ g, u16* __restrict__ out) {
  __shared__ float red[4];
  const int row = blockIdx.x, t = threadIdx.x;
  f32x4 v = ((const f32x4*)(x + (size_t)row * 1024))[t];
  float ss = v[0] * v[0] + v[1] * v[1] + v[2] * v[2] + v[3] * v[3];
#pragma unroll
  for (int off = 32; off >= 1; off >>= 1) ss += __shfl_xor(ss, off);
  if ((t & 63) == 0) red[t >> 6] = ss;
  __syncthreads();
  float tot = red[0] + red[1] + red[2] + red[3];
  float rinv = rsqrtf(tot * (1.f / 1024.f) + 1e-6f);
  f32x4 gg = ((const f32x4*)g)[t];
  float n[4];
#pragma unroll
  for (int j = 0; j < 4; ++j) n[j] = v[j] * rinv * gg[j];
  float gm = fmaxf(fmaxf(fabsf(n[0]), fabsf(n[1])), fmaxf(fabsf(n[2]), fabsf(n[3])));
#pragma unroll
  for (int off = 1; off <= 8; off <<= 1) gm = fmaxf(gm, __shfl_xor(gm, off));
  float s = fmaxf(gm, 1e-5f) / 127.0f;
  u16x4 o;
#pragma unroll
  for (int j = 0; j < 4; ++j) {
    float q = fminf(fmaxf(rintf(n[j] / s), -127.f), 127.f) * s;
    o[j] = f2bf(q);
  }
  ((u16x4*)out)[(size_t)row * 256 + t] = o;
}

// ---------------------------------------------------------------------------
// V transpose: qkv[:,2048+h*64 .. +63] -> Vt[h][d][t]  ([16][64][4096] bf16).
// Natural token order (R15).
// ---------------------------------------------------------------------------
__global__ __launch_bounds__(256) void transpose_v(
    const u16* __restrict__ qkv, u16* __restrict__ Vt) {
  __shared__ u16 T[64][65];
  const int tt = blockIdx.x, h = blockIdx.y, tid = threadIdx.x;
#pragma unroll
  for (int i = 0; i < 2; ++i) {
    int idx = i * 2048 + tid * 8;
    int trow = idx >> 6, dcol = idx & 63;
    u16x8 v = *(const u16x8*)(qkv + (size_t)(tt * 64 + trow) * 3072 + 2048 + h * 64 + dcol);
#pragma unroll
    for (int j = 0; j < 8; ++j) T[dcol + j][trow] = v[j];
  }
  __syncthreads();
#pragma unroll
  for (int i = 0; i < 2; ++i) {
    int idx = i * 2048 + tid * 8;
    int drow = idx >> 6, tcol = idx & 63;
    u16x8 v;
#pragma unroll
    for (int j = 0; j < 8; ++j) v[j] = T[drow][tcol + j];
    *(u16x8*)(Vt + ((size_t)h * 64 + drow) * 4096 + tt * 64 + tcol) = v;
  }
}

// ---------------------------------------------------------------------------
// GEMM: C[M,N] = alpha[bcol>>ashift] * (A[M,K] @ B[N,K]^T) (+res).
// BMx128 tile, BK=64, 4 waves, global_load_lds w=16, XOR swizzle.
// ---------------------------------------------------------------------------
template <bool RES, int BM>
__global__ __launch_bounds__(256) void gemm_bt(
    const u16* __restrict__ A, const u16* __restrict__ B,
    const float* __restrict__ alpha, int ashift, const float* __restrict__ res,
    void* __restrict__ Cout, int M, int N, int K) {
  constexpr int NI = (BM == 128) ? 4 : 2;
  constexpr int WNE = (BM == 128) ? 64 : 32;
  __shared__ u16 As[BM * 64];
  __shared__ u16 Bs[128 * 64];
  const int tid = threadIdx.x;
  const int l = tid & 63, w = tid >> 6;
  const int wm = (BM == 128) ? (w >> 1) : 0;
  const int wn = (BM == 128) ? (w & 1) : w;
  const int lr = l & 15, lg = l >> 4;
  const int xorv = (l & 7) << 4;
  const int brow = blockIdx.y * BM;
  const int bcol = blockIdx.x * 128;
  const int src_chunk = (l & 7) ^ (l >> 3);
  const int rl = w * 8 + (l >> 3);

  f32x4 acc[4][NI];
#pragma unroll
  for (int i = 0; i < 4; ++i)
#pragma unroll
    for (int j = 0; j < NI; ++j) acc[i][j] = (f32x4){0.f, 0.f, 0.f, 0.f};

  const char* Ag = (const char*)A;
  const char* Bg = (const char*)B;
  const int nkt = K >> 6;
  for (int kt = 0; kt < nkt; ++kt) {
    __syncthreads();
    const size_t kb = (size_t)kt * 128 + src_chunk * 16;
#pragma unroll
    for (int it = 0; it < BM / 32; ++it)
      gload16(Ag + (size_t)(brow + it * 32 + rl) * (size_t)(K * 2) + kb,
              &As[(it * 32 + w * 8) * 64]);
#pragma unroll
    for (int it = 0; it < 4; ++it)
      gload16(Bg + (size_t)(bcol + it * 32 + rl) * (size_t)(K * 2) + kb,
              &Bs[(it * 32 + w * 8) * 64]);
    __syncthreads();

    bf16x8 af[4][2], bfr[NI][2];
#pragma unroll
    for (int mi = 0; mi < 4; ++mi)
#pragma unroll
      for (int ks = 0; ks < 2; ++ks) {
        int row = wm * 64 + mi * 16 + lr;
        af[mi][ks] = *(const bf16x8*)((const char*)As + row * 128 + ((ks * 64 + lg * 16) ^ xorv));
      }
#pragma unroll
    for (int ni = 0; ni < NI; ++ni)
#pragma unroll
      for (int ks = 0; ks < 2; ++ks) {
        int row = wn * WNE + ni * 16 + lr;
        bfr[ni][ks] = *(const bf16x8*)((const char*)Bs + row * 128 + ((ks * 64 + lg * 16) ^ xorv));
      }
#pragma unroll
    for (int ks = 0; ks < 2; ++ks)
#pragma unroll
      for (int mi = 0; mi < 4; ++mi)
#pragma unroll
        for (int ni = 0; ni < NI; ++ni)
          acc[mi][ni] = __builtin_amdgcn_mfma_f32_16x16x32_bf16(
              af[mi][ks], bfr[ni][ks], acc[mi][ni], 0, 0, 0);
  }

  const float scale = alpha[bcol >> ashift];
#pragma unroll
  for (int mi = 0; mi < 4; ++mi)
#pragma unroll
    for (int ni = 0; ni < NI; ++ni)
#pragma unroll
      for (int r = 0; r < 4; ++r) {
        int row = brow + wm * 64 + mi * 16 + lg * 4 + r;
        int col = bcol + wn * WNE + ni * 16 + lr;
        float vv = acc[mi][ni][r] * scale;
        if (RES)
          ((float*)Cout)[(size_t)row * N + col] = res[(size_t)row * N + col] + vv;
        else
          ((u16*)Cout)[(size_t)row * N + col] = f2bf(vv);
      }
}

// ---------------------------------------------------------------------------
// Fat-wave GEMM: 256(M) x 128(N) tile, 4 waves, per-wave 128x64 output.
// 24 LDS reads / 64 MFMA per wave-iter. Used for the QKV projection.
// ---------------------------------------------------------------------------
template <bool RES>
__global__ __launch_bounds__(256, 2) void gemm_fat(
    const u16* __restrict__ A, const u16* __restrict__ B,
    const float* __restrict__ alpha, int ashift, const float* __restrict__ res,
    void* __restrict__ Cout, int M, int N, int K) {
  __shared__ u16 As[256 * 64];  // 32KB
  __shared__ u16 Bs[128 * 64];  // 16KB
  const int tid = threadIdx.x;
  const int l = tid & 63, w = tid >> 6;
  const int wm = w >> 1, wn = w & 1;
  const int lr = l & 15, lg = l >> 4;
  const int xorv = (l & 7) << 4;
  const int brow = blockIdx.y * 256;
  const int bcol = blockIdx.x * 128;
  const int src_chunk = (l & 7) ^ (l >> 3);
  const int rl = w * 8 + (l >> 3);

  f32x4 acc[8][4];
#pragma unroll
  for (int i = 0; i < 8; ++i)
#pragma unroll
    for (int j = 0; j < 4; ++j) acc[i][j] = (f32x4){0.f, 0.f, 0.f, 0.f};

  const int nkt = K >> 6;
  for (int kt = 0; kt < nkt; ++kt) {
    __syncthreads();
    const size_t kb = (size_t)kt * 128 + src_chunk * 16;
#pragma unroll
    for (int it = 0; it < 8; ++it)
      gload16((const char*)A + (size_t)(brow + it * 32 + rl) * (size_t)(K * 2) + kb,
              &As[(it * 32 + w * 8) * 64]);
#pragma unroll
    for (int it = 0; it < 4; ++it)
      gload16((const char*)B + (size_t)(bcol + it * 32 + rl) * (size_t)(K * 2) + kb,
              &Bs[(it * 32 + w * 8) * 64]);
    __syncthreads();

#pragma unroll
    for (int ks = 0; ks < 2; ++ks) {
      bf16x8 bfr[4];
#pragma unroll
      for (int ni = 0; ni < 4; ++ni)
        bfr[ni] = *(const bf16x8*)((const char*)Bs + (wn * 64 + ni * 16 + lr) * 128 +
                                   ((ks * 64 + lg * 16) ^ xorv));
#pragma unroll
      for (int mi = 0; mi < 8; ++mi) {
        bf16x8 af = *(const bf16x8*)((const char*)As + (wm * 128 + mi * 16 + lr) * 128 +
                                     ((ks * 64 + lg * 16) ^ xorv));
#pragma unroll
        for (int ni = 0; ni < 4; ++ni)
          acc[mi][ni] = __builtin_amdgcn_mfma_f32_16x16x32_bf16(
              af, bfr[ni], acc[mi][ni], 0, 0, 0);
      }
    }
  }

  const float scale = alpha[bcol >> ashift];
#pragma unroll
  for (int mi = 0; mi < 8; ++mi)
#pragma unroll
    for (int ni = 0; ni < 4; ++ni)
#pragma unroll
      for (int r = 0; r < 4; ++r) {
        int row = brow + wm * 128 + mi * 16 + lg * 4 + r;
        int col = bcol + wn * 64 + ni * 16 + lr;
        float vv = acc[mi][ni][r] * scale;
        if (RES)
          ((float*)Cout)[(size_t)row * N + col] = res[(size_t)row * N + col] + vv;
        else
          ((u16*)Cout)[(size_t)row * N + col] = f2bf(vv);
      }
}

// ---------------------------------------------------------------------------
// Fused FFN GEMM, fat-wave: tile 256(M) x 128(W12 rows = 64 z-cols),
// 4 waves, per-wave output 128x64 (acc 8x4). W12 fine-interleaved (16-row).
// ---------------------------------------------------------------------------
__global__ __launch_bounds__(256, 2) void gemm_ffn(
    const u16* __restrict__ A, const u16* __restrict__ B12,
    const float* __restrict__ alpha2, u16* __restrict__ zq) {
  __shared__ u16 As[256 * 64];  // 32KB
  __shared__ u16 Bs[128 * 64];  // 16KB
  const int tid = threadIdx.x;
  const int l = tid & 63, w = tid >> 6;
  const int wm = w >> 1, wn = w & 1;
  const int lr = l & 15, lg = l >> 4;
  const int xorv = (l & 7) << 4;
  const int brow = blockIdx.y * 256;
  const int bcol = blockIdx.x * 128;  // W12 row block = 64 z-cols
  const int src_chunk = (l & 7) ^ (l >> 3);
  const int rl = w * 8 + (l >> 3);

  f32x4 acc[8][4];
#pragma unroll
  for (int i = 0; i < 8; ++i)
#pragma unroll
    for (int j = 0; j < 4; ++j) acc[i][j] = (f32x4){0.f, 0.f, 0.f, 0.f};

  for (int kt = 0; kt < 16; ++kt) {
    __syncthreads();
    const size_t kb = (size_t)kt * 128 + src_chunk * 16;
#pragma unroll
    for (int it = 0; it < 8; ++it)
      gload16((const char*)A + (size_t)(brow + it * 32 + rl) * 2048 + kb,
              &As[(it * 32 + w * 8) * 64]);
#pragma unroll
    for (int it = 0; it < 4; ++it)
      gload16((const char*)B12 + (size_t)(bcol + it * 32 + rl) * 2048 + kb,
              &Bs[(it * 32 + w * 8) * 64]);
    __syncthreads();

#pragma unroll
    for (int ks = 0; ks < 2; ++ks) {
      bf16x8 bfr[4];
#pragma unroll
      for (int ni = 0; ni < 4; ++ni)
        bfr[ni] = *(const bf16x8*)((const char*)Bs + (wn * 64 + ni * 16 + lr) * 128 +
                                   ((ks * 64 + lg * 16) ^ xorv));
#pragma unroll
      for (int mi = 0; mi < 8; ++mi) {
        bf16x8 af = *(const bf16x8*)((const char*)As + (wm * 128 + mi * 16 + lr) * 128 +
                                     ((ks * 64 + lg * 16) ^ xorv));
#pragma unroll
        for (int ni = 0; ni < 4; ++ni)
          acc[mi][ni] = __builtin_amdgcn_mfma_f32_16x16x32_bf16(
              af, bfr[ni], acc[mi][ni], 0, 0, 0);
      }
    }
  }

  // ---- epilogue: z = silu(a1*y1)*(a2*y2) in-register ----
  const float a1 = alpha2[0], a2 = alpha2[1];
  const float L2E = 1.4426950408889634f;
  float zl[8][4], zh[8][4], rm[8][4];
#pragma unroll
  for (int mi = 0; mi < 8; ++mi)
#pragma unroll
    for (int r = 0; r < 4; ++r) {
      float y1 = acc[mi][0][r] * a1;
      zl[mi][r] = y1 / (1.f + fexp2(-L2E * y1)) * (acc[mi][1][r] * a2);
      float y3 = acc[mi][2][r] * a1;
      zh[mi][r] = y3 / (1.f + fexp2(-L2E * y3)) * (acc[mi][3][r] * a2);
      float g = fmaxf(fabsf(zl[mi][r]), fabsf(zh[mi][r]));
#pragma unroll
      for (int off = 1; off <= 8; off <<= 1) g = fmaxf(g, __shfl_xor(g, off));
      rm[mi][r] = g;  // this wave's 32-col max for the row
    }

  // cross-wave (wn pair: w and w^1 share wm) row-max via aliased staging LDS
  float* rmax = (float*)&As[0];  // [4][128] f32 = 2KB
  __syncthreads();               // all waves done reading staging
  if (lr == 0) {
#pragma unroll
    for (int mi = 0; mi < 8; ++mi)
#pragma unroll
      for (int r = 0; r < 4; ++r)
        rmax[w * 128 + mi * 16 + lg * 4 + r] = rm[mi][r];
  }
  __syncthreads();

#pragma unroll
  for (int mi = 0; mi < 8; ++mi)
#pragma unroll
    for (int r = 0; r < 4; ++r) {
      float g = fmaxf(rm[mi][r], rmax[(w ^ 1) * 128 + mi * 16 + lg * 4 + r]);
      float gmc = fmaxf(g, 1e-5f);
      float s = gmc * (1.f / 127.f);
      float inv = 127.f / gmc;
      int row = brow + wm * 128 + mi * 16 + lg * 4 + r;
      int zc = blockIdx.x * 64 + wn * 32 + lr;
      float q0 = fminf(fmaxf(rintf(zl[mi][r] * inv), -127.f), 127.f) * s;
      float q1 = fminf(fmaxf(rintf(zh[mi][r] * inv), -127.f), 127.f) * s;
      zq[(size_t)row * 4096 + zc] = f2bf(q0);
      zq[(size_t)row * 4096 + zc + 16] = f2bf(q1);
    }
}

// ---------------------------------------------------------------------------
// Causal flash attention + act_quant.  SWAPPED-OPERAND, TOKEN-SPLIT pairs
// (R15 structure), with conflict-free 128B-row P buffer (R11 pattern).
// QBLK=64, 8 waves: wave w -> q-group wq=w&3, token half tw=w>>2.
// Grid (16 heads, 64): qt = y<32?y:95-y (balanced, 130 slots/CU). LDS 48KB.
// ---------------------------------------------------------------------------
__global__ __launch_bounds__(512) void attn_kernel(
    const u16* __restrict__ QKV, const u16* __restrict__ Vt, u16* __restrict__ Y) {
  __shared__ u16 Ks[2][64 * 64];  // [k-token 64][d 64] swizzled, 16KB
  __shared__ u16 Vs[2][64 * 64];  // [d 64][k-token 64] swizzled, 16KB
  __shared__ u16 Ps[8][16 * 64];  // per-wave P^T [16 q][64-wide rows], 16KB

  const int tid = threadIdx.x;
  const int l = tid & 63, w = tid >> 6;  // 8 waves
  const int wq = w & 3, tw = w >> 2;     // q-group, token half
  const int lr = l & 15, lg = l >> 4;
  const int xorv = (l & 7) << 4;
  const int h = blockIdx.x;
  const int y = blockIdx.y;
  const int qt = (y < 32) ? y : (95 - y);  // 64-row q-tile index
  const int rl = w * 8 + (l >> 3);         // staging row 0..63
  const float SC = 0.18033688f;            // 0.125 * log2(e)

  const int qrow0 = qt * 64 + wq * 16;     // this wave's first q row
  const int nkt = qt + 1;

  bf16x8 qf[2];
#pragma unroll
  for (int ks = 0; ks < 2; ++ks)
    qf[ks] = __builtin_bit_cast(
        bf16x8, *(const u16x8*)(QKV + (size_t)(qrow0 + lr) * 3072 +
                                h * 64 + ks * 32 + lg * 8));

  f32x4 O[4];  // O^T: lane holds O[q=qrow0+lr][d = ni*16 + lg*4 + r] (partial)
#pragma unroll
  for (int ni = 0; ni < 4; ++ni) O[ni] = (f32x4){0.f, 0.f, 0.f, 0.f};
  float m_ = -3e38f, lsum = 0.f;

  auto STAGE = [&](int buf, int kt) {
    int krow = kt * 64 + rl;
    gload16((const char*)QKV + ((size_t)krow * 3072 + 1024 + h * 64) * 2 +
                ((l & 7) ^ (l >> 3)) * 16,
            &Ks[buf][(w * 8) * 64]);
    gload16((const char*)Vt + (((size_t)h * 64 + rl) * 4096 + kt * 64) * 2 +
                ((l & 7) ^ (l >> 3)) * 16,
            &Vs[buf][(w * 8) * 64]);
  };

  STAGE(0, 0);
#pragma unroll 1
  for (int kt = 0; kt < nkt; ++kt) {
    const int cur = kt & 1;
    if (kt + 1 < nkt) {
      STAGE(cur ^ 1, kt + 1);
      asm volatile("s_waitcnt vmcnt(2)" ::: "memory");  // current tile's 2 done
    } else {
      asm volatile("s_waitcnt vmcnt(0)" ::: "memory");
    }
    __builtin_amdgcn_s_barrier();
    __builtin_amdgcn_sched_barrier(0);

    const char* kbase = (const char*)&Ks[cur][0];
    const char* vbase = (const char*)&Vs[cur][0];

    // S^T[ni] = mfma(K, Q): tokens tw*32 + ni*16 + lr (ni in {0,1})
    f32x4 S[2];
    __builtin_amdgcn_s_setprio(1);
#pragma unroll
    for (int ni = 0; ni < 2; ++ni) {
      S[ni] = (f32x4){0.f, 0.f, 0.f, 0.f};
#pragma unroll
      for (int ks = 0; ks < 2; ++ks) {
        bf16x8 kf = *(const bf16x8*)(kbase + (tw * 32 + ni * 16 + lr) * 128 +
                                     ((ks * 64 + lg * 16) ^ xorv));
        S[ni] = __builtin_amdgcn_mfma_f32_16x16x32_bf16(kf, qf[ks], S[ni], 0, 0, 0);
      }
    }
    __builtin_amdgcn_s_setprio(0);

    // V fragments (4 d-tiles, this wave's 32 tokens)
    bf16x8 vf[4];
#pragma unroll
    for (int ni = 0; ni < 4; ++ni)
      vf[ni] = *(const bf16x8*)(vbase + (ni * 16 + lr) * 128 +
                                ((tw * 64 + lg * 16) ^ xorv));

    // causal mask on raw S
    const int tb = kt * 64 + tw * 32;
    if (tb + 31 > qrow0) {
#pragma unroll
      for (int ni = 0; ni < 2; ++ni)
#pragma unroll
        for (int r = 0; r < 4; ++r)
          if (tb + ni * 16 + lg * 4 + r > qrow0 + lr) S[ni][r] = -3e38f;
    }

    // online softmax over this wave's 32 tokens (row spans 4 lg-lanes)
    float nm = fmaxf(fmaxf(S[0][0], S[0][1]), fmaxf(S[0][2], S[0][3]));
    nm = fmaxf(nm, fmaxf(fmaxf(S[1][0], S[1][1]), fmaxf(S[1][2], S[1][3])));
    nm = fmaxf(nm, __shfl_xor(nm, 16));
    nm = fmaxf(nm, __shfl_xor(nm, 32));
    float nms = nm * SC;
    if (__ballot(nms > m_ + 8.f)) {  // T13 defer-rescale
      float mn = fmaxf(m_, nms);
      float fac = fexp2(m_ - mn);
      m_ = mn;
      lsum *= fac;
#pragma unroll
      for (int ni = 0; ni < 4; ++ni) O[ni] *= fac;
    }
    float rs = 0.f;
#pragma unroll
    for (int ni = 0; ni < 2; ++ni)
#pragma unroll
      for (int r = 0; r < 4; ++r) {
        float pv = fexp2(__builtin_fmaf(S[ni][r], SC, -m_));
        S[ni][r] = pv;
        rs += pv;
      }
    rs += __shfl_xor(rs, 16);
    rs += __shfl_xor(rs, 32);
    lsum += rs;

    // P^T -> wave-private LDS [16 q][64-wide rows], 128B rows + xorv swizzle
    // (2-way bank aliasing only; R11-proven pattern)
#pragma unroll
    for (int ni = 0; ni < 2; ++ni) {
      u32x2 pk;
      pk[0] = cvtpk(S[ni][0], S[ni][1]);
      pk[1] = cvtpk(S[ni][2], S[ni][3]);
      *(u32x2*)((char*)&Ps[w][0] + lr * 128 + ((ni * 32 + lg * 8) ^ xorv)) = pk;
    }
    bf16x8 pt = *(const bf16x8*)((const char*)&Ps[w][0] + lr * 128 +
                                 ((lg * 16) ^ xorv));

    // O^T[ni] += mfma(V^T, P^T)  (K=32: one mfma per d-tile)
    __builtin_amdgcn_s_setprio(1);
#pragma unroll
    for (int ni = 0; ni < 4; ++ni)
      O[ni] = __builtin_amdgcn_mfma_f32_16x16x32_bf16(vf[ni], pt, O[ni], 0, 0, 0);
    __builtin_amdgcn_s_setprio(0);
    asm volatile("" ::: "memory");
    __builtin_amdgcn_s_barrier();  // protect buf before next STAGE overwrites
  }

  // ---- epilogue: merge token halves, normalize, act_quant ----
  __syncthreads();  // all waves done with staging buffers
  float* exO = (float*)&Vs[0][0];  // [4 pair][64 lane][16] f32 = 16KB
  float* exM = (float*)&Ks[0][0];  // [4 pair][64 lane][2] f32 = 2KB
  if (tw == 1) {
#pragma unroll
    for (int ni = 0; ni < 4; ++ni)
      *(f32x4*)&exO[(size_t)wq * 1024 + l * 16 + ni * 4] = O[ni];
    exM[wq * 128 + l * 2] = m_;
    exM[wq * 128 + l * 2 + 1] = lsum;
  }
  __syncthreads();
  if (tw == 0) {
    float mh = exM[wq * 128 + l * 2];
    float lh = exM[wq * 128 + l * 2 + 1];
    float M = fmaxf(m_, mh);
    float a = fexp2(m_ - M);
    float b = fexp2(mh - M);
    float ls = a * lsum + b * lh;
    float rinv = 1.f / ls;
    float o[4][4];
    float gm = 0.f;
#pragma unroll
    for (int ni = 0; ni < 4; ++ni) {
      f32x4 Oh = *(const f32x4*)&exO[(size_t)wq * 1024 + l * 16 + ni * 4];
#pragma unroll
      for (int r = 0; r < 4; ++r) {
        o[ni][r] = (a * O[ni][r] + b * Oh[r]) * rinv;
        gm = fmaxf(gm, fabsf(o[ni][r]));
      }
    }
    gm = fmaxf(gm, __shfl_xor(gm, 16));
    gm = fmaxf(gm, __shfl_xor(gm, 32));
    float gmc = fmaxf(gm, 1e-5f);
    float s = gmc * (1.f / 127.f);
    float inv = 127.f / gmc;
#pragma unroll
    for (int ni = 0; ni < 4; ++ni) {
      u16x4 ov;
#pragma unroll
      for (int r = 0; r < 4; ++r) {
        float q = fminf(fmaxf(rintf(o[ni][r] * inv), -127.f), 127.f) * s;
        ov[r] = f2bf(q);
      }
      *(u16x4*)(Y + (size_t)(qrow0 + lr) * 1024 + h * 64 + ni * 16 + lg * 4) = ov;
    }
  }
}

// ---------------------------------------------------------------------------
extern "C" void kernel_launch(void* const* d_in, const int* in_sizes, int n_in,
                              void* d_out, int out_size, void* d_ws, size_t ws_size,
                              hipStream_t stream) {
  const float* x  = (const float*)d_in[0];
  const float* wq = (const float*)d_in[1];
  const float* wk = (const float*)d_in[2];
  const float* wv = (const float*)d_in[3];
  const float* wo = (const float*)d_in[4];
  const float* w1 = (const float*)d_in[5];
  const float* w2 = (const float*)d_in[6];
  const float* w3 = (const float*)d_in[7];
  const float* g1 = (const float*)d_in[8];
  const float* g2 = (const float*)d_in[9];

  char* ws = (char*)d_ws;
  const size_t MB = 1024 * 1024;
  u16* sgn   = (u16*)ws;
  u16* sWq   = (u16*)(ws + 0 * MB);
  u16* sWo   = (u16*)(ws + 6 * MB);
  u16* sW12  = (u16*)(ws + 8 * MB);    // fine-interleaved [8192,1024]
  u16* sW3   = (u16*)(ws + 24 * MB);
  float* partial = (float*)(ws + 32 * MB);
  float* alphas  = (float*)(ws + 32 * MB + 16384);
  u16* Vt    = (u16*)(ws + 33 * MB);   // dead before x1 written
  float* x1  = (float*)(ws + 33 * MB); // fp32 [4096,1024]
  u16* hq    = (u16*)(ws + 49 * MB);   // bf16 [4096,1024]
  u16* qkv   = (u16*)(ws + 57 * MB);   // bf16 [4096,3072]
  u16* yb    = (u16*)(ws + 81 * MB);   // bf16 [4096,1024]
  u16* zq    = (u16*)(ws + 57 * MB);   // bf16 [4096,4096] (qkv,yb dead)

  // weight prep + rmsnorm#1 (y==7) fused
  convert_sign_all<<<dim3(256, 8), 256, 0, stream>>>(wq, wk, wv, wo, w1, w2, w3,
                                                     sgn, partial, x, g1, hq);
  finalize_alpha<<<7, 256, 0, stream>>>(partial, alphas);

  // attention branch
  gemm_fat<false><<<dim3(24, 16), 256, 0, stream>>>(hq, sWq, alphas, 10, nullptr,
                                                    qkv, 4096, 3072, 1024);
  transpose_v<<<dim3(64, 16), 256, 0, stream>>>(qkv, Vt);
  attn_kernel<<<dim3(16, 64), 512, 0, stream>>>(qkv, Vt, yb);
  gemm_bt<true, 64><<<dim3(8, 64), 256, 0, stream>>>(yb, sWo, alphas + 3, 31, x,
                                                     x1, 4096, 1024, 1024);
  // FFN branch
  rmsnorm_quant<<<4096, 256, 0, stream>>>(x1, g2, hq);
  gemm_ffn<<<dim3(64, 16), 256, 0, stream>>>(hq, sW12, alphas + 4, zq);
  gemm_bt<true, 64><<<dim3(8, 64), 256, 0, stream>>>(zq, sW3, alphas + 6, 31, x1,
                                                     (float*)d_out, 4096, 1024, 4096);
}